// Round 1
// baseline (2075.481 us; speedup 1.0000x reference)
//
#include <hip/hip_runtime.h>
#include <hip/hip_bf16.h>
#include <stdint.h>

#define NN   100000
#define ICH  256
#define HID  128
#define OUTF 64

__device__ __forceinline__ float bf2f(uint16_t u){
  union { uint32_t i; float f; } v; v.i = ((uint32_t)u) << 16; return v.f;
}
__device__ __forceinline__ uint16_t f2bf(float f){
  union { float f; uint32_t i; } v; v.f = f;
  uint32_t i = v.i;
  return (uint16_t)((i + 0x7FFFu + ((i >> 16) & 1u)) >> 16);
}
__device__ __forceinline__ uint32_t pack2(float a, float b){
  return (uint32_t)f2bf(a) | ((uint32_t)f2bf(b) << 16);
}

__global__ void k_deg(const int* __restrict__ row, int E, int* __restrict__ deg){
  int i = blockIdx.x * blockDim.x + threadIdx.x;
  if (i < E) atomicAdd(&deg[row[i]], 1);
}

__global__ void k_r(const int* __restrict__ deg, float* __restrict__ r, int n){
  int i = blockIdx.x * blockDim.x + threadIdx.x;
  if (i < n) r[i] = 1.0f / (float)(deg[i] + 1);
}

// edges are sorted by src (row) -> CSR row_ptr via per-node binary search
__global__ void k_rowptr(const int* __restrict__ row, int E, int n, int* __restrict__ rp){
  int i = blockIdx.x * blockDim.x + threadIdx.x;
  if (i <= n){
    int lo = 0, hi = E;
    while (lo < hi){
      int mid = (lo + hi) >> 1;
      if (row[mid] < i) lo = mid + 1; else hi = mid;
    }
    rp[i] = lo;
  }
}

// h = relu(x @ W_lin1 + b_lin1), stored bf16.  64-node x 128-col tile per block.
__launch_bounds__(256)
__global__ void k_lin1(const float* __restrict__ x, const float* __restrict__ W,
                       const float* __restrict__ b, uint16_t* __restrict__ h){
  __shared__ float xs[64][33];
  int tid = threadIdx.x;
  int node0 = blockIdx.x * 64;
  int rr = (tid >> 4) * 4;   // node row base within tile
  int cc = (tid & 15) * 8;   // col base
  float acc[4][8];
  #pragma unroll
  for (int i = 0; i < 4; ++i)
    #pragma unroll
    for (int j = 0; j < 8; ++j) acc[i][j] = 0.f;

  for (int k0 = 0; k0 < ICH; k0 += 32){
    __syncthreads();
    #pragma unroll
    for (int t = 0; t < 8; ++t){
      int idx = tid + t * 256;
      int r_ = idx >> 5, c_ = idx & 31;
      int nd = node0 + r_;
      xs[r_][c_] = (nd < NN) ? x[(size_t)nd * ICH + k0 + c_] : 0.f;
    }
    __syncthreads();
    #pragma unroll 8
    for (int kk = 0; kk < 32; ++kk){
      const float4* wp = (const float4*)(W + (size_t)(k0 + kk) * HID + cc);
      float4 wa = wp[0], wb = wp[1];
      float wv[8] = {wa.x, wa.y, wa.z, wa.w, wb.x, wb.y, wb.z, wb.w};
      float xv[4] = {xs[rr + 0][kk], xs[rr + 1][kk], xs[rr + 2][kk], xs[rr + 3][kk]};
      #pragma unroll
      for (int i = 0; i < 4; ++i)
        #pragma unroll
        for (int j = 0; j < 8; ++j) acc[i][j] += xv[i] * wv[j];
    }
  }
  float bias[8];
  #pragma unroll
  for (int j = 0; j < 8; ++j) bias[j] = b[cc + j];
  #pragma unroll
  for (int i = 0; i < 4; ++i){
    int nd = node0 + rr + i;
    if (nd < NN){
      uint32_t* dst = (uint32_t*)(h + (size_t)nd * HID + cc);
      #pragma unroll
      for (int j2 = 0; j2 < 4; ++j2){
        float v0 = acc[i][2*j2]   + bias[2*j2];   v0 = v0 > 0.f ? v0 : 0.f;
        float v1 = acc[i][2*j2+1] + bias[2*j2+1]; v1 = v1 > 0.f ? v1 : 0.f;
        dst[j2] = pack2(v0, v1);
      }
    }
  }
}

// one wave per node: P = S h, T1 = S(r.h), T2 = S(r^2.h) in a single gather pass
__launch_bounds__(256)
__global__ void k_spmmA(const int* __restrict__ col, const int* __restrict__ rp,
                        const float* __restrict__ r, const uint32_t* __restrict__ h,
                        uint32_t* __restrict__ P, uint32_t* __restrict__ T1,
                        uint32_t* __restrict__ T2){
  int wid  = (blockIdx.x * blockDim.x + threadIdx.x) >> 6;
  int lane = threadIdx.x & 63;
  if (wid >= NN) return;
  int e0 = rp[wid], e1 = rp[wid + 1];
  float a0 = 0, b0 = 0, a1 = 0, b1 = 0, a2 = 0, b2 = 0;
  for (int e = e0; e < e1; ++e){
    int j = col[e];
    float rj = r[j];
    uint32_t hv = h[(size_t)j * 64 + lane];
    float x0 = bf2f((uint16_t)hv), x1 = bf2f((uint16_t)(hv >> 16));
    float r2 = rj * rj;
    a0 += x0;      b0 += x1;
    a1 += rj * x0; b1 += rj * x1;
    a2 += r2 * x0; b2 += r2 * x1;
  }
  size_t o = (size_t)wid * 64 + lane;
  P[o]  = pack2(a0, b0);
  T1[o] = pack2(a1, b1);
  T2[o] = pack2(a2, b2);
}

// Q1 = S(r.P), Q2 = S(r^2.P)
__launch_bounds__(256)
__global__ void k_spmmB(const int* __restrict__ col, const int* __restrict__ rp,
                        const float* __restrict__ r, const uint32_t* __restrict__ Pm,
                        uint32_t* __restrict__ Q1, uint32_t* __restrict__ Q2){
  int wid  = (blockIdx.x * blockDim.x + threadIdx.x) >> 6;
  int lane = threadIdx.x & 63;
  if (wid >= NN) return;
  int e0 = rp[wid], e1 = rp[wid + 1];
  float a1 = 0, b1 = 0, a2 = 0, b2 = 0;
  for (int e = e0; e < e1; ++e){
    int j = col[e];
    float rj = r[j];
    uint32_t pv = Pm[(size_t)j * 64 + lane];
    float x0 = bf2f((uint16_t)pv), x1 = bf2f((uint16_t)(pv >> 16));
    float r2 = rj * rj;
    a1 += rj * x0; b1 += rj * x1;
    a2 += r2 * x0; b2 += r2 * x1;
  }
  size_t o = (size_t)wid * 64 + lane;
  Q1[o] = pack2(a1, b1);
  Q2[o] = pack2(a2, b2);
}

// Fused 4-layer epilogue + lin2.  Per 64-node tile:
//  for each layer: build M1,M2 (node-wise combos of h,P,T1,T2,Q1,Q2) in LDS,
//  acc += relu(M1 @ W1[l]) + relu(M2 @ W2[l]); finally out = (acc/8) @ W_lin2 + b2.
__launch_bounds__(256)
__global__ void k_epi(const uint32_t* __restrict__ h,  const uint32_t* __restrict__ P,
                      const uint32_t* __restrict__ T1, const uint32_t* __restrict__ T2,
                      const uint32_t* __restrict__ Q1, const uint32_t* __restrict__ Q2,
                      const float* __restrict__ r,
                      const float* __restrict__ W1, const float* __restrict__ W2,
                      const float* __restrict__ Wl2, const float* __restrict__ b2,
                      float* __restrict__ out){
  __shared__ float M1[64][132];
  __shared__ float M2[64][132];
  int tid = threadIdx.x;
  int node0 = blockIdx.x * 64;

  // M-compute ownership: thread owns 32 consecutive feats (16 uints) of one node
  int nb = tid >> 2;            // 0..63 node within tile
  int fu = (tid & 3) * 16;      // uint base (2 feats per uint)
  int nd = node0 + nb;
  bool valid = nd < NN;
  size_t bofs = (size_t)nd * 64 + fu;
  float rv = valid ? r[nd] : 1.f;

  // GEMM ownership: 4 nodes x 8 cols per thread
  int gr = (tid >> 4) * 4;
  int gc = (tid & 15) * 8;
  float acc[4][8];
  #pragma unroll
  for (int i = 0; i < 4; ++i)
    #pragma unroll
    for (int j = 0; j < 8; ++j) acc[i][j] = 0.f;

  #pragma unroll
  for (int l = 0; l < 4; ++l){
    __syncthreads();   // previous-layer GEMM reads done before rewriting M
    if (valid){
      #pragma unroll 4
      for (int u = 0; u < 16; ++u){
        uint32_t vh = h[bofs+u],  vP = P[bofs+u],  vA = T1[bofs+u];
        uint32_t vB = T2[bofs+u], vC = Q1[bofs+u], vD = Q2[bofs+u];
        #pragma unroll
        for (int s = 0; s < 2; ++s){
          float hh = bf2f((uint16_t)(s ? (vh>>16) : vh));
          float pp = bf2f((uint16_t)(s ? (vP>>16) : vP));
          float t1 = bf2f((uint16_t)(s ? (vA>>16) : vA));
          float t2 = bf2f((uint16_t)(s ? (vB>>16) : vB));
          float q1 = bf2f((uint16_t)(s ? (vC>>16) : vC));
          float q2 = bf2f((uint16_t)(s ? (vD>>16) : vD));
          float m1v, m2v;
          if (l == 0){
            float F = rv * (pp + hh);
            m1v = F; m2v = hh - F;
          } else if (l == 1){
            float F = rv * (pp + hh);
            float G = hh - F;
            m1v = rv * (pp - q1 - t1 + G);
            m2v = F - rv * (q1 + t1 + F);
          } else if (l == 2){
            float omr = 1.f - rv;
            float G2 = rv*rv*pp + omr*omr*hh;
            m1v = rv * (q2 + pp - 2.f*t1 + t2 + G2);
            float F2 = rv*rv*(pp + hh);
            m2v = F2 - rv * (q2 + t2 + F2);
          } else {
            float omr = 1.f - rv;
            float r3 = rv*rv*rv;
            m1v = omr*omr*omr*hh - r3*pp;
            m2v = r3 * (pp + hh);
          }
          int f = (fu + u) * 2 + s;
          M1[nb][f] = m1v;
          M2[nb][f] = m2v;
        }
      }
    } else {
      #pragma unroll
      for (int u = 0; u < 16; ++u){
        int f = (fu + u) * 2;
        M1[nb][f] = 0.f; M1[nb][f+1] = 0.f;
        M2[nb][f] = 0.f; M2[nb][f+1] = 0.f;
      }
    }
    __syncthreads();

    {
      float t[4][8];
      #pragma unroll
      for (int i = 0; i < 4; ++i)
        #pragma unroll
        for (int j = 0; j < 8; ++j) t[i][j] = 0.f;
      const float* Wp = W1 + (size_t)l * HID * HID;
      #pragma unroll 4
      for (int k = 0; k < HID; ++k){
        const float4* wp = (const float4*)(Wp + (size_t)k * HID + gc);
        float4 wa = wp[0], wb = wp[1];
        float wv[8] = {wa.x, wa.y, wa.z, wa.w, wb.x, wb.y, wb.z, wb.w};
        float mv[4] = {M1[gr+0][k], M1[gr+1][k], M1[gr+2][k], M1[gr+3][k]};
        #pragma unroll
        for (int i = 0; i < 4; ++i)
          #pragma unroll
          for (int j = 0; j < 8; ++j) t[i][j] += mv[i] * wv[j];
      }
      #pragma unroll
      for (int i = 0; i < 4; ++i)
        #pragma unroll
        for (int j = 0; j < 8; ++j) acc[i][j] += (t[i][j] > 0.f ? t[i][j] : 0.f);
    }
    {
      float t[4][8];
      #pragma unroll
      for (int i = 0; i < 4; ++i)
        #pragma unroll
        for (int j = 0; j < 8; ++j) t[i][j] = 0.f;
      const float* Wp = W2 + (size_t)l * HID * HID;
      #pragma unroll 4
      for (int k = 0; k < HID; ++k){
        const float4* wp = (const float4*)(Wp + (size_t)k * HID + gc);
        float4 wa = wp[0], wb = wp[1];
        float wv[8] = {wa.x, wa.y, wa.z, wa.w, wb.x, wb.y, wb.z, wb.w};
        float mv[4] = {M2[gr+0][k], M2[gr+1][k], M2[gr+2][k], M2[gr+3][k]};
        #pragma unroll
        for (int i = 0; i < 4; ++i)
          #pragma unroll
          for (int j = 0; j < 8; ++j) t[i][j] += mv[i] * wv[j];
      }
      #pragma unroll
      for (int i = 0; i < 4; ++i)
        #pragma unroll
        for (int j = 0; j < 8; ++j) acc[i][j] += (t[i][j] > 0.f ? t[i][j] : 0.f);
    }
  }

  // lin2: stage acc/8 in LDS (reuse M1), then 64x64 GEMM
  __syncthreads();
  #pragma unroll
  for (int i = 0; i < 4; ++i)
    #pragma unroll
    for (int j = 0; j < 8; ++j) M1[gr+i][gc+j] = acc[i][j] * 0.125f;
  __syncthreads();

  int oc = (tid & 15) * 4;
  float t2[4][4];
  #pragma unroll
  for (int i = 0; i < 4; ++i)
    #pragma unroll
    for (int j = 0; j < 4; ++j) t2[i][j] = 0.f;
  #pragma unroll 4
  for (int k = 0; k < HID; ++k){
    float4 w = *(const float4*)(Wl2 + (size_t)k * OUTF + oc);
    float wv[4] = {w.x, w.y, w.z, w.w};
    float mv[4] = {M1[gr+0][k], M1[gr+1][k], M1[gr+2][k], M1[gr+3][k]};
    #pragma unroll
    for (int i = 0; i < 4; ++i)
      #pragma unroll
      for (int j = 0; j < 4; ++j) t2[i][j] += mv[i] * wv[j];
  }
  float bb[4] = {b2[oc], b2[oc+1], b2[oc+2], b2[oc+3]};
  #pragma unroll
  for (int i = 0; i < 4; ++i){
    int ndo = node0 + gr + i;
    if (ndo < NN){
      float4 o4 = make_float4(t2[i][0]+bb[0], t2[i][1]+bb[1], t2[i][2]+bb[2], t2[i][3]+bb[3]);
      *(float4*)(out + (size_t)ndo * OUTF + oc) = o4;
    }
  }
}

extern "C" void kernel_launch(void* const* d_in, const int* in_sizes, int n_in,
                              void* d_out, int out_size, void* d_ws, size_t ws_size,
                              hipStream_t stream){
  const float* x   = (const float*)d_in[0];
  const float* Wl1 = (const float*)d_in[1];
  const float* bl1 = (const float*)d_in[2];
  const float* W1  = (const float*)d_in[3];
  const float* W2  = (const float*)d_in[4];
  const float* Wl2 = (const float*)d_in[5];
  const float* bl2 = (const float*)d_in[6];
  const int*   ei  = (const int*)d_in[7];
  int E = in_sizes[7] / 2;
  const int* rowp = ei;
  const int* colp = ei + E;

  char* ws = (char*)d_ws;
  size_t off = 0;
  auto alloc = [&](size_t bytes) -> void* {
    void* p = ws + off;
    off += (bytes + 255) & ~(size_t)255;
    return p;
  };
  const size_t MATB = (size_t)NN * HID * 2;   // bf16 node-matrix bytes
  uint32_t* h  = (uint32_t*)alloc(MATB);
  uint32_t* P  = (uint32_t*)alloc(MATB);
  uint32_t* T1 = (uint32_t*)alloc(MATB);
  uint32_t* T2 = (uint32_t*)alloc(MATB);
  uint32_t* Q1 = (uint32_t*)alloc(MATB);
  uint32_t* Q2 = (uint32_t*)alloc(MATB);
  float* r  = (float*)alloc((size_t)NN * 4);
  int* deg  = (int*)alloc((size_t)NN * 4);
  int* rp   = (int*)alloc((size_t)(NN + 1) * 4);

  hipMemsetAsync(deg, 0, (size_t)NN * 4, stream);
  k_deg<<<(E + 255) / 256, 256, 0, stream>>>(rowp, E, deg);
  k_r<<<(NN + 255) / 256, 256, 0, stream>>>(deg, r, NN);
  k_rowptr<<<(NN + 1 + 255) / 256, 256, 0, stream>>>(rowp, E, NN, rp);
  k_lin1<<<(NN + 63) / 64, 256, 0, stream>>>(x, Wl1, bl1, (uint16_t*)h);
  k_spmmA<<<(NN + 3) / 4, 256, 0, stream>>>(colp, rp, r, h, P, T1, T2);
  k_spmmB<<<(NN + 3) / 4, 256, 0, stream>>>(colp, rp, r, P, Q1, Q2);
  k_epi<<<(NN + 63) / 64, 256, 0, stream>>>(h, P, T1, T2, Q1, Q2, r,
                                            W1, W2, Wl2, bl2, (float*)d_out);
}

// Round 2
// 1099.198 us; speedup vs baseline: 1.8882x; 1.8882x over previous
//
#include <hip/hip_runtime.h>
#include <hip/hip_bf16.h>
#include <stdint.h>

#define NN   100000
#define ICH  256
#define HID  128
#define OUTF 64

typedef float  f32x4  __attribute__((ext_vector_type(4)));
typedef __bf16 bf16x8 __attribute__((ext_vector_type(8)));

__device__ __forceinline__ float bf2f(uint16_t u){
  union { uint32_t i; float f; } v; v.i = ((uint32_t)u) << 16; return v.f;
}
__device__ __forceinline__ uint16_t f2bf(float f){
  union { float f; uint32_t i; } v; v.f = f;
  uint32_t i = v.i;
  return (uint16_t)((i + 0x7FFFu + ((i >> 16) & 1u)) >> 16);
}
__device__ __forceinline__ uint32_t pack2(float a, float b){
  return (uint32_t)f2bf(a) | ((uint32_t)f2bf(b) << 16);
}

__global__ void k_deg(const int* __restrict__ row, int E, int* __restrict__ deg){
  int i = blockIdx.x * blockDim.x + threadIdx.x;
  if (i < E) atomicAdd(&deg[row[i]], 1);
}

__global__ void k_r(const int* __restrict__ deg, float* __restrict__ r, int n){
  int i = blockIdx.x * blockDim.x + threadIdx.x;
  if (i < n) r[i] = 1.0f / (float)(deg[i] + 1);
}

__global__ void k_rowptr(const int* __restrict__ row, int E, int n, int* __restrict__ rp){
  int i = blockIdx.x * blockDim.x + threadIdx.x;
  if (i <= n){
    int lo = 0, hi = E;
    while (lo < hi){
      int mid = (lo + hi) >> 1;
      if (row[mid] < i) lo = mid + 1; else hi = mid;
    }
    rp[i] = lo;
  }
}

// bf16-transpose weights: W1T[l][n][k] = W1[l][k][n]; W2T likewise; Wl2T[n][k] = Wl2[k][n]
__global__ void k_wprep(const float* __restrict__ W1, const float* __restrict__ W2,
                        const float* __restrict__ Wl2,
                        uint16_t* __restrict__ W1T, uint16_t* __restrict__ W2T,
                        uint16_t* __restrict__ Wl2T){
  int idx = blockIdx.x * blockDim.x + threadIdx.x;
  if (idx < 4 * 128 * 128){
    int l = idx >> 14, rem = idx & 16383, n = rem >> 7, k = rem & 127;
    W1T[idx] = f2bf(W1[l * 16384 + k * 128 + n]);
    W2T[idx] = f2bf(W2[l * 16384 + k * 128 + n]);
  }
  if (idx < 64 * 128){
    int n = idx >> 7, k = idx & 127;
    Wl2T[idx] = f2bf(Wl2[k * 64 + n]);
  }
}

// h = relu(x @ W_lin1 + b_lin1), stored bf16.
__launch_bounds__(256)
__global__ void k_lin1(const float* __restrict__ x, const float* __restrict__ W,
                       const float* __restrict__ b, uint16_t* __restrict__ h){
  __shared__ float xs[64][33];
  int tid = threadIdx.x;
  int node0 = blockIdx.x * 64;
  int rr = (tid >> 4) * 4;
  int cc = (tid & 15) * 8;
  float acc[4][8];
  #pragma unroll
  for (int i = 0; i < 4; ++i)
    #pragma unroll
    for (int j = 0; j < 8; ++j) acc[i][j] = 0.f;

  for (int k0 = 0; k0 < ICH; k0 += 32){
    __syncthreads();
    #pragma unroll
    for (int t = 0; t < 8; ++t){
      int idx = tid + t * 256;
      int r_ = idx >> 5, c_ = idx & 31;
      int nd = node0 + r_;
      xs[r_][c_] = (nd < NN) ? x[(size_t)nd * ICH + k0 + c_] : 0.f;
    }
    __syncthreads();
    #pragma unroll 8
    for (int kk = 0; kk < 32; ++kk){
      const float4* wp = (const float4*)(W + (size_t)(k0 + kk) * HID + cc);
      float4 wa = wp[0], wb = wp[1];
      float wv[8] = {wa.x, wa.y, wa.z, wa.w, wb.x, wb.y, wb.z, wb.w};
      float xv[4] = {xs[rr + 0][kk], xs[rr + 1][kk], xs[rr + 2][kk], xs[rr + 3][kk]};
      #pragma unroll
      for (int i = 0; i < 4; ++i)
        #pragma unroll
        for (int j = 0; j < 8; ++j) acc[i][j] += xv[i] * wv[j];
    }
  }
  float bias[8];
  #pragma unroll
  for (int j = 0; j < 8; ++j) bias[j] = b[cc + j];
  #pragma unroll
  for (int i = 0; i < 4; ++i){
    int nd = node0 + rr + i;
    if (nd < NN){
      uint32_t* dst = (uint32_t*)(h + (size_t)nd * HID + cc);
      #pragma unroll
      for (int j2 = 0; j2 < 4; ++j2){
        float v0 = acc[i][2*j2]   + bias[2*j2];   v0 = v0 > 0.f ? v0 : 0.f;
        float v1 = acc[i][2*j2+1] + bias[2*j2+1]; v1 = v1 > 0.f ? v1 : 0.f;
        dst[j2] = pack2(v0, v1);
      }
    }
  }
}

// one wave per node: P = S h, T1 = S(r.h), T2 = S(r^2.h)
__launch_bounds__(256)
__global__ void k_spmmA(const int* __restrict__ col, const int* __restrict__ rp,
                        const float* __restrict__ r, const uint32_t* __restrict__ h,
                        uint32_t* __restrict__ P, uint32_t* __restrict__ T1,
                        uint32_t* __restrict__ T2){
  int wid  = (blockIdx.x * blockDim.x + threadIdx.x) >> 6;
  int lane = threadIdx.x & 63;
  if (wid >= NN) return;
  int e0 = rp[wid], e1 = rp[wid + 1];
  float a0 = 0, b0 = 0, a1 = 0, b1 = 0, a2 = 0, b2 = 0;
  for (int e = e0; e < e1; ++e){
    int j = col[e];
    float rj = r[j];
    uint32_t hv = h[(size_t)j * 64 + lane];
    float x0 = bf2f((uint16_t)hv), x1 = bf2f((uint16_t)(hv >> 16));
    float r2 = rj * rj;
    a0 += x0;      b0 += x1;
    a1 += rj * x0; b1 += rj * x1;
    a2 += r2 * x0; b2 += r2 * x1;
  }
  size_t o = (size_t)wid * 64 + lane;
  P[o]  = pack2(a0, b0);
  T1[o] = pack2(a1, b1);
  T2[o] = pack2(a2, b2);
}

// Q1 = S(r.P), Q2 = S(r^2.P)
__launch_bounds__(256)
__global__ void k_spmmB(const int* __restrict__ col, const int* __restrict__ rp,
                        const float* __restrict__ r, const uint32_t* __restrict__ Pm,
                        uint32_t* __restrict__ Q1, uint32_t* __restrict__ Q2){
  int wid  = (blockIdx.x * blockDim.x + threadIdx.x) >> 6;
  int lane = threadIdx.x & 63;
  if (wid >= NN) return;
  int e0 = rp[wid], e1 = rp[wid + 1];
  float a1 = 0, b1 = 0, a2 = 0, b2 = 0;
  for (int e = e0; e < e1; ++e){
    int j = col[e];
    float rj = r[j];
    uint32_t pv = Pm[(size_t)j * 64 + lane];
    float x0 = bf2f((uint16_t)pv), x1 = bf2f((uint16_t)(pv >> 16));
    float r2 = rj * rj;
    a1 += rj * x0; b1 += rj * x1;
    a2 += r2 * x0; b2 += r2 * x1;
  }
  size_t o = (size_t)wid * 64 + lane;
  Q1[o] = pack2(a1, b1);
  Q2[o] = pack2(a2, b2);
}

__device__ __forceinline__ void ld4u(const uint32_t* p, uint32_t a[4]){
  uint4 t = *(const uint4*)p;
  a[0] = t.x; a[1] = t.y; a[2] = t.z; a[3] = t.w;
}

// MFMA epilogue: per 64-node tile, for l in 0..3: build M1,M2 (bf16, LDS),
// acc += relu(M1@W1[l]) + relu(M2@W2[l]); then out = (acc/8)@Wl2 + b2.
// Wave w owns output cols [32w,32w+32) (B-frag reuse across 4 row-tiles).
__launch_bounds__(256)
__global__ void k_epi2(const uint32_t* __restrict__ h,  const uint32_t* __restrict__ P,
                       const uint32_t* __restrict__ T1, const uint32_t* __restrict__ T2,
                       const uint32_t* __restrict__ Q1, const uint32_t* __restrict__ Q2,
                       const float* __restrict__ r,
                       const uint16_t* __restrict__ W1T, const uint16_t* __restrict__ W2T,
                       const uint16_t* __restrict__ Wl2T, const float* __restrict__ b2,
                       float* __restrict__ out){
  __shared__ __align__(16) uint32_t Mu[2][64][68];   // bf16 [64][136] each, row stride 272B
  const int tid = threadIdx.x;
  const int node0 = blockIdx.x * 64;

  // build-phase ownership: 4 threads per node, thread covers 4 x 16B chunks
  const int nb = tid >> 2;
  const int qc = tid & 3;
  const int nd = node0 + nb;
  const bool valid = nd < NN;
  const float rv = valid ? r[nd] : 1.f;
  const size_t ub = (size_t)nd * 64;   // uint32 row base

  // gemm ownership
  const int wv   = tid >> 6;
  const int lane = tid & 63;
  const int lr   = lane & 15;
  const int lg   = lane >> 4;

  f32x4 acc[4][2];
  #pragma unroll
  for (int rt = 0; rt < 4; ++rt)
    #pragma unroll
    for (int n2 = 0; n2 < 2; ++n2)
      acc[rt][n2] = (f32x4){0.f, 0.f, 0.f, 0.f};

  #pragma unroll
  for (int l = 0; l < 4; ++l){
    __syncthreads();   // previous GEMM reads done before rewriting M
    // ---- build M1,M2 ----
    #pragma unroll
    for (int c = 0; c < 4; ++c){
      const int ui = qc * 4 + c * 16;      // uint index within node row
      uint32_t ah[4], ap[4], at1[4], at2[4], aq1[4], aq2[4];
      uint32_t o1[4], o2[4];
      if (valid){
        ld4u(h + ub + ui, ah);
        ld4u(P + ub + ui, ap);
        if (l == 1){ ld4u(Q1 + ub + ui, aq1); ld4u(T1 + ub + ui, at1); }
        if (l == 2){ ld4u(Q2 + ub + ui, aq2); ld4u(T1 + ub + ui, at1); ld4u(T2 + ub + ui, at2); }
        #pragma unroll
        for (int wq = 0; wq < 4; ++wq){
          float m1s[2], m2s[2];
          #pragma unroll
          for (int s = 0; s < 2; ++s){
            float hh = bf2f((uint16_t)(s ? (ah[wq] >> 16) : ah[wq]));
            float pp = bf2f((uint16_t)(s ? (ap[wq] >> 16) : ap[wq]));
            if (l == 0){
              float F = rv * (pp + hh);
              m1s[s] = F; m2s[s] = hh - F;
            } else if (l == 1){
              float t1 = bf2f((uint16_t)(s ? (at1[wq] >> 16) : at1[wq]));
              float q1 = bf2f((uint16_t)(s ? (aq1[wq] >> 16) : aq1[wq]));
              float F = rv * (pp + hh);
              float G = hh - F;
              m1s[s] = rv * (pp - q1 - t1 + G);
              m2s[s] = F - rv * (q1 + t1 + F);
            } else if (l == 2){
              float t1 = bf2f((uint16_t)(s ? (at1[wq] >> 16) : at1[wq]));
              float t2 = bf2f((uint16_t)(s ? (at2[wq] >> 16) : at2[wq]));
              float q2 = bf2f((uint16_t)(s ? (aq2[wq] >> 16) : aq2[wq]));
              float omr = 1.f - rv;
              float G2 = rv * rv * pp + omr * omr * hh;
              m1s[s] = rv * (q2 + pp - 2.f * t1 + t2 + G2);
              float F2 = rv * rv * (pp + hh);
              m2s[s] = F2 - rv * (q2 + t2 + F2);
            } else {
              float omr = 1.f - rv;
              float r3 = rv * rv * rv;
              m1s[s] = omr * omr * omr * hh - r3 * pp;
              m2s[s] = r3 * (pp + hh);
            }
          }
          o1[wq] = pack2(m1s[0], m1s[1]);
          o2[wq] = pack2(m2s[0], m2s[1]);
        }
      } else {
        #pragma unroll
        for (int wq = 0; wq < 4; ++wq){ o1[wq] = 0u; o2[wq] = 0u; }
      }
      *(uint4*)&Mu[0][nb][ui] = make_uint4(o1[0], o1[1], o1[2], o1[3]);
      *(uint4*)&Mu[1][nb][ui] = make_uint4(o2[0], o2[1], o2[2], o2[3]);
    }
    __syncthreads();

    // ---- MFMA: acc += relu(M @ W) for M1/W1 and M2/W2 ----
    #pragma unroll
    for (int m = 0; m < 2; ++m){
      const uint16_t* Wt = (m ? W2T : W1T) + (size_t)l * 128 * 128;
      bf16x8 bfr[2][4];
      #pragma unroll
      for (int n2 = 0; n2 < 2; ++n2){
        const int n = (2 * wv + n2) * 16 + lr;
        const uint16_t* bp = Wt + (size_t)n * 128 + lg * 8;
        #pragma unroll
        for (int ks = 0; ks < 4; ++ks)
          bfr[n2][ks] = __builtin_bit_cast(bf16x8, *(const uint4*)(bp + ks * 32));
      }
      #pragma unroll
      for (int rt = 0; rt < 4; ++rt){
        const int row = rt * 16 + lr;
        bf16x8 af[4];
        #pragma unroll
        for (int ks = 0; ks < 4; ++ks)
          af[ks] = __builtin_bit_cast(bf16x8, *(const uint4*)&Mu[m][row][ks * 16 + lg * 4]);
        #pragma unroll
        for (int n2 = 0; n2 < 2; ++n2){
          f32x4 d = (f32x4){0.f, 0.f, 0.f, 0.f};
          #pragma unroll
          for (int ks = 0; ks < 4; ++ks)
            d = __builtin_amdgcn_mfma_f32_16x16x32_bf16(af[ks], bfr[n2][ks], d, 0, 0, 0);
          #pragma unroll
          for (int q = 0; q < 4; ++q)
            acc[rt][n2][q] += (d[q] > 0.f ? d[q] : 0.f);
        }
      }
    }
  }

  // ---- lin2: stage acc/8 as bf16 in Mu[0], then 64x128x64 MFMA ----
  __syncthreads();
  uint16_t* Mb = (uint16_t*)&Mu[0][0][0];   // row stride 136 bf16
  #pragma unroll
  for (int rt = 0; rt < 4; ++rt)
    #pragma unroll
    for (int n2 = 0; n2 < 2; ++n2)
      #pragma unroll
      for (int q = 0; q < 4; ++q){
        int row = rt * 16 + lg * 4 + q;
        int colb = (2 * wv + n2) * 16 + lr;
        Mb[row * 136 + colb] = f2bf(acc[rt][n2][q] * 0.125f);
      }
  __syncthreads();

  const int arow = 16 * wv + lr;    // wave w handles rows [16w,16w+16)
  bf16x8 af2[4];
  #pragma unroll
  for (int ks = 0; ks < 4; ++ks)
    af2[ks] = __builtin_bit_cast(bf16x8, *(const uint4*)&Mu[0][arow][ks * 16 + lg * 4]);
  #pragma unroll
  for (int nt = 0; nt < 4; ++nt){
    f32x4 d = (f32x4){0.f, 0.f, 0.f, 0.f};
    #pragma unroll
    for (int ks = 0; ks < 4; ++ks){
      bf16x8 bfr = __builtin_bit_cast(bf16x8,
          *(const uint4*)(Wl2T + (size_t)(nt * 16 + lr) * 128 + ks * 32 + lg * 8));
      d = __builtin_amdgcn_mfma_f32_16x16x32_bf16(af2[ks], bfr, d, 0, 0, 0);
    }
    float bias = b2[nt * 16 + lr];
    #pragma unroll
    for (int q = 0; q < 4; ++q){
      int rr = node0 + 16 * wv + lg * 4 + q;
      if (rr < NN) out[(size_t)rr * OUTF + nt * 16 + lr] = d[q] + bias;
    }
  }
}

extern "C" void kernel_launch(void* const* d_in, const int* in_sizes, int n_in,
                              void* d_out, int out_size, void* d_ws, size_t ws_size,
                              hipStream_t stream){
  const float* x   = (const float*)d_in[0];
  const float* Wl1 = (const float*)d_in[1];
  const float* bl1 = (const float*)d_in[2];
  const float* W1  = (const float*)d_in[3];
  const float* W2  = (const float*)d_in[4];
  const float* Wl2 = (const float*)d_in[5];
  const float* bl2 = (const float*)d_in[6];
  const int*   ei  = (const int*)d_in[7];
  int E = in_sizes[7] / 2;
  const int* rowp = ei;
  const int* colp = ei + E;

  char* ws = (char*)d_ws;
  size_t off = 0;
  auto alloc = [&](size_t bytes) -> void* {
    void* p = ws + off;
    off += (bytes + 255) & ~(size_t)255;
    return p;
  };
  const size_t MATB = (size_t)NN * HID * 2;   // bf16 node-matrix bytes
  uint32_t* h  = (uint32_t*)alloc(MATB);
  uint32_t* P  = (uint32_t*)alloc(MATB);
  uint32_t* T1 = (uint32_t*)alloc(MATB);
  uint32_t* T2 = (uint32_t*)alloc(MATB);
  uint32_t* Q1 = (uint32_t*)alloc(MATB);
  uint32_t* Q2 = (uint32_t*)alloc(MATB);
  float* r  = (float*)alloc((size_t)NN * 4);
  int* deg  = (int*)alloc((size_t)NN * 4);
  int* rp   = (int*)alloc((size_t)(NN + 1) * 4);
  uint16_t* W1T  = (uint16_t*)alloc((size_t)4 * 128 * 128 * 2);
  uint16_t* W2T  = (uint16_t*)alloc((size_t)4 * 128 * 128 * 2);
  uint16_t* Wl2T = (uint16_t*)alloc((size_t)64 * 128 * 2);

  hipMemsetAsync(deg, 0, (size_t)NN * 4, stream);
  k_wprep<<<(4 * 128 * 128 + 255) / 256, 256, 0, stream>>>(W1, W2, Wl2, W1T, W2T, Wl2T);
  k_deg<<<(E + 255) / 256, 256, 0, stream>>>(rowp, E, deg);
  k_r<<<(NN + 255) / 256, 256, 0, stream>>>(deg, r, NN);
  k_rowptr<<<(NN + 1 + 255) / 256, 256, 0, stream>>>(rowp, E, NN, rp);
  k_lin1<<<(NN + 63) / 64, 256, 0, stream>>>(x, Wl1, bl1, (uint16_t*)h);
  k_spmmA<<<(NN + 3) / 4, 256, 0, stream>>>(colp, rp, r, h, P, T1, T2);
  k_spmmB<<<(NN + 3) / 4, 256, 0, stream>>>(colp, rp, r, P, Q1, Q2);
  k_epi2<<<(NN + 63) / 64, 256, 0, stream>>>(h, P, T1, T2, Q1, Q2, r,
                                             W1T, W2T, Wl2T, bl2, (float*)d_out);
}

// Round 3
// 758.727 us; speedup vs baseline: 2.7355x; 1.4487x over previous
//
#include <hip/hip_runtime.h>
#include <hip/hip_bf16.h>
#include <stdint.h>

#define NN   100000
#define ICH  256
#define HID  128
#define OUTF 64

typedef float  f32x4  __attribute__((ext_vector_type(4)));
typedef __bf16 bf16x8 __attribute__((ext_vector_type(8)));

__device__ __forceinline__ float bf2f(uint16_t u){
  union { uint32_t i; float f; } v; v.i = ((uint32_t)u) << 16; return v.f;
}
__device__ __forceinline__ uint16_t f2bf(float f){
  union { float f; uint32_t i; } v; v.f = f;
  uint32_t i = v.i;
  return (uint16_t)((i + 0x7FFFu + ((i >> 16) & 1u)) >> 16);
}
__device__ __forceinline__ uint32_t pack2(float a, float b){
  return (uint32_t)f2bf(a) | ((uint32_t)f2bf(b) << 16);
}

__global__ void k_deg(const int* __restrict__ row, int E, int* __restrict__ deg){
  int i = blockIdx.x * blockDim.x + threadIdx.x;
  if (i < E) atomicAdd(&deg[row[i]], 1);
}

__global__ void k_r(const int* __restrict__ deg, float* __restrict__ r, int n){
  int i = blockIdx.x * blockDim.x + threadIdx.x;
  if (i < n) r[i] = 1.0f / (float)(deg[i] + 1);
}

__global__ void k_rowptr(const int* __restrict__ row, int E, int n, int* __restrict__ rp){
  int i = blockIdx.x * blockDim.x + threadIdx.x;
  if (i <= n){
    int lo = 0, hi = E;
    while (lo < hi){
      int mid = (lo + hi) >> 1;
      if (row[mid] < i) lo = mid + 1; else hi = mid;
    }
    rp[i] = lo;
  }
}

// bf16-transpose weights: W1T/W2T [l][n][k], Wl1T [n][k] (k<256), Wl2T [n][k]
__global__ void k_wprep(const float* __restrict__ W1, const float* __restrict__ W2,
                        const float* __restrict__ Wl1, const float* __restrict__ Wl2,
                        uint16_t* __restrict__ W1T, uint16_t* __restrict__ W2T,
                        uint16_t* __restrict__ Wl1T, uint16_t* __restrict__ Wl2T){
  int idx = blockIdx.x * blockDim.x + threadIdx.x;
  if (idx < 4 * 128 * 128){
    int l = idx >> 14, rem = idx & 16383, n = rem >> 7, k = rem & 127;
    W1T[idx] = f2bf(W1[l * 16384 + k * 128 + n]);
    W2T[idx] = f2bf(W2[l * 16384 + k * 128 + n]);
  }
  if (idx < 128 * 256){
    int n = idx >> 8, k = idx & 255;
    Wl1T[idx] = f2bf(Wl1[k * 128 + n]);
  }
  if (idx < 64 * 128){
    int n = idx >> 7, k = idx & 127;
    Wl2T[idx] = f2bf(Wl2[k * 64 + n]);
  }
}

// h = relu(x @ W_lin1 + b) via MFMA. 64-node tile, wave w owns cols [32w,32w+32).
__launch_bounds__(256)
__global__ void k_lin1m(const float* __restrict__ x, const uint16_t* __restrict__ Wl1T,
                        const float* __restrict__ b, uint16_t* __restrict__ h){
  __shared__ __align__(16) uint16_t Xs[64][264];   // 256 + 8 pad, row stride 528B
  const int tid = threadIdx.x;
  const int node0 = blockIdx.x * 64;
  const int wv = tid >> 6, lane = tid & 63, lr = lane & 15, lg = lane >> 4;

  // stage x -> bf16 LDS, fully coalesced float4 loads
  #pragma unroll
  for (int i = 0; i < 16; ++i){
    int fi = tid + i * 256;
    int rrow = fi >> 6, c4 = (fi & 63) * 4;
    int nd = node0 + rrow;
    float4 f = (nd < NN) ? *(const float4*)(x + (size_t)nd * ICH + c4)
                         : make_float4(0.f, 0.f, 0.f, 0.f);
    *(uint2*)&Xs[rrow][c4] = make_uint2(pack2(f.x, f.y), pack2(f.z, f.w));
  }
  __syncthreads();

  // B fragments: wave's 2 col-tiles, K=256 -> 8 ksteps
  bf16x8 bfr[2][8];
  #pragma unroll
  for (int n2 = 0; n2 < 2; ++n2){
    const int n = (2 * wv + n2) * 16 + lr;
    const uint16_t* bp = Wl1T + (size_t)n * 256 + lg * 8;
    #pragma unroll
    for (int ks = 0; ks < 8; ++ks)
      bfr[n2][ks] = __builtin_bit_cast(bf16x8, *(const uint4*)(bp + ks * 32));
  }
  float bias[2] = {b[(2 * wv + 0) * 16 + lr], b[(2 * wv + 1) * 16 + lr]};

  #pragma unroll
  for (int rt = 0; rt < 4; ++rt){
    const int row = rt * 16 + lr;
    bf16x8 af[8];
    #pragma unroll
    for (int ks = 0; ks < 8; ++ks)
      af[ks] = __builtin_bit_cast(bf16x8, *(const uint4*)&Xs[row][ks * 32 + lg * 8]);
    #pragma unroll
    for (int n2 = 0; n2 < 2; ++n2){
      f32x4 d = (f32x4){0.f, 0.f, 0.f, 0.f};
      #pragma unroll
      for (int ks = 0; ks < 8; ++ks)
        d = __builtin_amdgcn_mfma_f32_16x16x32_bf16(af[ks], bfr[n2][ks], d, 0, 0, 0);
      const int ncol = (2 * wv + n2) * 16 + lr;
      #pragma unroll
      for (int q = 0; q < 4; ++q){
        int nd = node0 + rt * 16 + lg * 4 + q;
        if (nd < NN){
          float v = d[q] + bias[n2];
          h[(size_t)nd * HID + ncol] = f2bf(v > 0.f ? v : 0.f);
        }
      }
    }
  }
}

// one wave per node: P = S h, T1 = S(r.h), T2 = S(r^2.h)
// chunked: coalesced col/r loads per 64 edges, readlane broadcast, unrolled h-gather
__launch_bounds__(256)
__global__ void k_spmmA(const int* __restrict__ col, const int* __restrict__ rp,
                        const float* __restrict__ r, const uint32_t* __restrict__ h,
                        uint32_t* __restrict__ P, uint32_t* __restrict__ T1,
                        uint32_t* __restrict__ T2){
  int wid  = (blockIdx.x * blockDim.x + threadIdx.x) >> 6;
  int lane = threadIdx.x & 63;
  if (wid >= NN) return;
  int e0 = rp[wid], e1 = rp[wid + 1];
  float a0 = 0, b0 = 0, a1 = 0, b1 = 0, a2 = 0, b2 = 0;
  for (int base = e0; base < e1; base += 64){
    int tot = e1 - base;
    int cnt = tot < 64 ? tot : 64;
    int   jv  = (lane < cnt) ? col[base + lane] : 0;
    float rvv = (lane < cnt) ? r[jv] : 0.f;
    int rvb  = __builtin_bit_cast(int, rvv);
    int r2b  = __builtin_bit_cast(int, rvv * rvv);
    #pragma unroll 4
    for (int k = 0; k < cnt; ++k){
      int   j  = __builtin_amdgcn_readlane(jv, k);
      float rj = __builtin_bit_cast(float, __builtin_amdgcn_readlane(rvb, k));
      float r2 = __builtin_bit_cast(float, __builtin_amdgcn_readlane(r2b, k));
      uint32_t hv = h[(size_t)j * 64 + lane];
      float x0 = bf2f((uint16_t)hv), x1 = bf2f((uint16_t)(hv >> 16));
      a0 += x0;      b0 += x1;
      a1 += rj * x0; b1 += rj * x1;
      a2 += r2 * x0; b2 += r2 * x1;
    }
  }
  size_t o = (size_t)wid * 64 + lane;
  P[o]  = pack2(a0, b0);
  T1[o] = pack2(a1, b1);
  T2[o] = pack2(a2, b2);
}

// Q1 = S(r.P), Q2 = S(r^2.P)
__launch_bounds__(256)
__global__ void k_spmmB(const int* __restrict__ col, const int* __restrict__ rp,
                        const float* __restrict__ r, const uint32_t* __restrict__ Pm,
                        uint32_t* __restrict__ Q1, uint32_t* __restrict__ Q2){
  int wid  = (blockIdx.x * blockDim.x + threadIdx.x) >> 6;
  int lane = threadIdx.x & 63;
  if (wid >= NN) return;
  int e0 = rp[wid], e1 = rp[wid + 1];
  float a1 = 0, b1 = 0, a2 = 0, b2 = 0;
  for (int base = e0; base < e1; base += 64){
    int tot = e1 - base;
    int cnt = tot < 64 ? tot : 64;
    int   jv  = (lane < cnt) ? col[base + lane] : 0;
    float rvv = (lane < cnt) ? r[jv] : 0.f;
    int rvb  = __builtin_bit_cast(int, rvv);
    int r2b  = __builtin_bit_cast(int, rvv * rvv);
    #pragma unroll 4
    for (int k = 0; k < cnt; ++k){
      int   j  = __builtin_amdgcn_readlane(jv, k);
      float rj = __builtin_bit_cast(float, __builtin_amdgcn_readlane(rvb, k));
      float r2 = __builtin_bit_cast(float, __builtin_amdgcn_readlane(r2b, k));
      uint32_t pv = Pm[(size_t)j * 64 + lane];
      float x0 = bf2f((uint16_t)pv), x1 = bf2f((uint16_t)(pv >> 16));
      a1 += rj * x0; b1 += rj * x1;
      a2 += r2 * x0; b2 += r2 * x1;
    }
  }
  size_t o = (size_t)wid * 64 + lane;
  Q1[o] = pack2(a1, b1);
  Q2[o] = pack2(a2, b2);
}

__device__ __forceinline__ void ld4u(const uint32_t* p, uint32_t a[4]){
  uint4 t = *(const uint4*)p;
  a[0] = t.x; a[1] = t.y; a[2] = t.z; a[3] = t.w;
}

// MFMA epilogue (unchanged from R2)
__launch_bounds__(256)
__global__ void k_epi2(const uint32_t* __restrict__ h,  const uint32_t* __restrict__ P,
                       const uint32_t* __restrict__ T1, const uint32_t* __restrict__ T2,
                       const uint32_t* __restrict__ Q1, const uint32_t* __restrict__ Q2,
                       const float* __restrict__ r,
                       const uint16_t* __restrict__ W1T, const uint16_t* __restrict__ W2T,
                       const uint16_t* __restrict__ Wl2T, const float* __restrict__ b2,
                       float* __restrict__ out){
  __shared__ __align__(16) uint32_t Mu[2][64][68];   // bf16 [64][136], row stride 272B
  const int tid = threadIdx.x;
  const int node0 = blockIdx.x * 64;

  const int nb = tid >> 2;
  const int qc = tid & 3;
  const int nd = node0 + nb;
  const bool valid = nd < NN;
  const float rv = valid ? r[nd] : 1.f;
  const size_t ub = (size_t)nd * 64;

  const int wv   = tid >> 6;
  const int lane = tid & 63;
  const int lr   = lane & 15;
  const int lg   = lane >> 4;

  f32x4 acc[4][2];
  #pragma unroll
  for (int rt = 0; rt < 4; ++rt)
    #pragma unroll
    for (int n2 = 0; n2 < 2; ++n2)
      acc[rt][n2] = (f32x4){0.f, 0.f, 0.f, 0.f};

  #pragma unroll
  for (int l = 0; l < 4; ++l){
    __syncthreads();
    #pragma unroll
    for (int c = 0; c < 4; ++c){
      const int ui = qc * 4 + c * 16;
      uint32_t ah[4], ap[4], at1[4], at2[4], aq1[4], aq2[4];
      uint32_t o1[4], o2[4];
      if (valid){
        ld4u(h + ub + ui, ah);
        ld4u(P + ub + ui, ap);
        if (l == 1){ ld4u(Q1 + ub + ui, aq1); ld4u(T1 + ub + ui, at1); }
        if (l == 2){ ld4u(Q2 + ub + ui, aq2); ld4u(T1 + ub + ui, at1); ld4u(T2 + ub + ui, at2); }
        #pragma unroll
        for (int wq = 0; wq < 4; ++wq){
          float m1s[2], m2s[2];
          #pragma unroll
          for (int s = 0; s < 2; ++s){
            float hh = bf2f((uint16_t)(s ? (ah[wq] >> 16) : ah[wq]));
            float pp = bf2f((uint16_t)(s ? (ap[wq] >> 16) : ap[wq]));
            if (l == 0){
              float F = rv * (pp + hh);
              m1s[s] = F; m2s[s] = hh - F;
            } else if (l == 1){
              float t1 = bf2f((uint16_t)(s ? (at1[wq] >> 16) : at1[wq]));
              float q1 = bf2f((uint16_t)(s ? (aq1[wq] >> 16) : aq1[wq]));
              float F = rv * (pp + hh);
              float G = hh - F;
              m1s[s] = rv * (pp - q1 - t1 + G);
              m2s[s] = F - rv * (q1 + t1 + F);
            } else if (l == 2){
              float t1 = bf2f((uint16_t)(s ? (at1[wq] >> 16) : at1[wq]));
              float t2 = bf2f((uint16_t)(s ? (at2[wq] >> 16) : at2[wq]));
              float q2 = bf2f((uint16_t)(s ? (aq2[wq] >> 16) : aq2[wq]));
              float omr = 1.f - rv;
              float G2 = rv * rv * pp + omr * omr * hh;
              m1s[s] = rv * (q2 + pp - 2.f * t1 + t2 + G2);
              float F2 = rv * rv * (pp + hh);
              m2s[s] = F2 - rv * (q2 + t2 + F2);
            } else {
              float omr = 1.f - rv;
              float r3 = rv * rv * rv;
              m1s[s] = omr * omr * omr * hh - r3 * pp;
              m2s[s] = r3 * (pp + hh);
            }
          }
          o1[wq] = pack2(m1s[0], m1s[1]);
          o2[wq] = pack2(m2s[0], m2s[1]);
        }
      } else {
        #pragma unroll
        for (int wq = 0; wq < 4; ++wq){ o1[wq] = 0u; o2[wq] = 0u; }
      }
      *(uint4*)&Mu[0][nb][ui] = make_uint4(o1[0], o1[1], o1[2], o1[3]);
      *(uint4*)&Mu[1][nb][ui] = make_uint4(o2[0], o2[1], o2[2], o2[3]);
    }
    __syncthreads();

    #pragma unroll
    for (int m = 0; m < 2; ++m){
      const uint16_t* Wt = (m ? W2T : W1T) + (size_t)l * 128 * 128;
      bf16x8 bfr[2][4];
      #pragma unroll
      for (int n2 = 0; n2 < 2; ++n2){
        const int n = (2 * wv + n2) * 16 + lr;
        const uint16_t* bp = Wt + (size_t)n * 128 + lg * 8;
        #pragma unroll
        for (int ks = 0; ks < 4; ++ks)
          bfr[n2][ks] = __builtin_bit_cast(bf16x8, *(const uint4*)(bp + ks * 32));
      }
      #pragma unroll
      for (int rt = 0; rt < 4; ++rt){
        const int row = rt * 16 + lr;
        bf16x8 af[4];
        #pragma unroll
        for (int ks = 0; ks < 4; ++ks)
          af[ks] = __builtin_bit_cast(bf16x8, *(const uint4*)&Mu[m][row][ks * 16 + lg * 4]);
        #pragma unroll
        for (int n2 = 0; n2 < 2; ++n2){
          f32x4 d = (f32x4){0.f, 0.f, 0.f, 0.f};
          #pragma unroll
          for (int ks = 0; ks < 4; ++ks)
            d = __builtin_amdgcn_mfma_f32_16x16x32_bf16(af[ks], bfr[n2][ks], d, 0, 0, 0);
          #pragma unroll
          for (int q = 0; q < 4; ++q)
            acc[rt][n2][q] += (d[q] > 0.f ? d[q] : 0.f);
        }
      }
    }
  }

  __syncthreads();
  uint16_t* Mb = (uint16_t*)&Mu[0][0][0];
  #pragma unroll
  for (int rt = 0; rt < 4; ++rt)
    #pragma unroll
    for (int n2 = 0; n2 < 2; ++n2)
      #pragma unroll
      for (int q = 0; q < 4; ++q){
        int row = rt * 16 + lg * 4 + q;
        int colb = (2 * wv + n2) * 16 + lr;
        Mb[row * 136 + colb] = f2bf(acc[rt][n2][q] * 0.125f);
      }
  __syncthreads();

  const int arow = 16 * wv + lr;
  bf16x8 af2[4];
  #pragma unroll
  for (int ks = 0; ks < 4; ++ks)
    af2[ks] = __builtin_bit_cast(bf16x8, *(const uint4*)&Mu[0][arow][ks * 16 + lg * 4]);
  #pragma unroll
  for (int nt = 0; nt < 4; ++nt){
    f32x4 d = (f32x4){0.f, 0.f, 0.f, 0.f};
    #pragma unroll
    for (int ks = 0; ks < 4; ++ks){
      bf16x8 bfr = __builtin_bit_cast(bf16x8,
          *(const uint4*)(Wl2T + (size_t)(nt * 16 + lr) * 128 + ks * 32 + lg * 8));
      d = __builtin_amdgcn_mfma_f32_16x16x32_bf16(af2[ks], bfr, d, 0, 0, 0);
    }
    float bias = b2[nt * 16 + lr];
    #pragma unroll
    for (int q = 0; q < 4; ++q){
      int rr = node0 + 16 * wv + lg * 4 + q;
      if (rr < NN) out[(size_t)rr * OUTF + nt * 16 + lr] = d[q] + bias;
    }
  }
}

extern "C" void kernel_launch(void* const* d_in, const int* in_sizes, int n_in,
                              void* d_out, int out_size, void* d_ws, size_t ws_size,
                              hipStream_t stream){
  const float* x   = (const float*)d_in[0];
  const float* Wl1 = (const float*)d_in[1];
  const float* bl1 = (const float*)d_in[2];
  const float* W1  = (const float*)d_in[3];
  const float* W2  = (const float*)d_in[4];
  const float* Wl2 = (const float*)d_in[5];
  const float* bl2 = (const float*)d_in[6];
  const int*   ei  = (const int*)d_in[7];
  int E = in_sizes[7] / 2;
  const int* rowp = ei;
  const int* colp = ei + E;

  char* ws = (char*)d_ws;
  size_t off = 0;
  auto alloc = [&](size_t bytes) -> void* {
    void* p = ws + off;
    off += (bytes + 255) & ~(size_t)255;
    return p;
  };
  const size_t MATB = (size_t)NN * HID * 2;
  uint32_t* h  = (uint32_t*)alloc(MATB);
  uint32_t* P  = (uint32_t*)alloc(MATB);
  uint32_t* T1 = (uint32_t*)alloc(MATB);
  uint32_t* T2 = (uint32_t*)alloc(MATB);
  uint32_t* Q1 = (uint32_t*)alloc(MATB);
  uint32_t* Q2 = (uint32_t*)alloc(MATB);
  float* r  = (float*)alloc((size_t)NN * 4);
  int* deg  = (int*)alloc((size_t)NN * 4);
  int* rp   = (int*)alloc((size_t)(NN + 1) * 4);
  uint16_t* W1T  = (uint16_t*)alloc((size_t)4 * 128 * 128 * 2);
  uint16_t* W2T  = (uint16_t*)alloc((size_t)4 * 128 * 128 * 2);
  uint16_t* Wl1T = (uint16_t*)alloc((size_t)128 * 256 * 2);
  uint16_t* Wl2T = (uint16_t*)alloc((size_t)64 * 128 * 2);

  hipMemsetAsync(deg, 0, (size_t)NN * 4, stream);
  k_wprep<<<(4 * 128 * 128 + 255) / 256, 256, 0, stream>>>(W1, W2, Wl1, Wl2,
                                                           W1T, W2T, Wl1T, Wl2T);
  k_deg<<<(E + 255) / 256, 256, 0, stream>>>(rowp, E, deg);
  k_r<<<(NN + 255) / 256, 256, 0, stream>>>(deg, r, NN);
  k_rowptr<<<(NN + 1 + 255) / 256, 256, 0, stream>>>(rowp, E, NN, rp);
  k_lin1m<<<(NN + 63) / 64, 256, 0, stream>>>(x, Wl1T, bl1, (uint16_t*)h);
  k_spmmA<<<(NN + 3) / 4, 256, 0, stream>>>(colp, rp, r, h, P, T1, T2);
  k_spmmB<<<(NN + 3) / 4, 256, 0, stream>>>(colp, rp, r, P, Q1, Q2);
  k_epi2<<<(NN + 63) / 64, 256, 0, stream>>>(h, P, T1, T2, Q1, Q2, r,
                                             W1T, W2T, Wl2T, bl2, (float*)d_out);
}

// Round 4
// 605.050 us; speedup vs baseline: 3.4303x; 1.2540x over previous
//
#include <hip/hip_runtime.h>
#include <hip/hip_bf16.h>
#include <stdint.h>

#define NN   100000
#define ICH  256
#define HID  128
#define OUTF 64

typedef float  f32x4  __attribute__((ext_vector_type(4)));
typedef __bf16 bf16x8 __attribute__((ext_vector_type(8)));

__device__ __forceinline__ float bf2f(uint16_t u){
  union { uint32_t i; float f; } v; v.i = ((uint32_t)u) << 16; return v.f;
}
__device__ __forceinline__ uint16_t f2bf(float f){
  union { float f; uint32_t i; } v; v.f = f;
  uint32_t i = v.i;
  return (uint16_t)((i + 0x7FFFu + ((i >> 16) & 1u)) >> 16);
}
__device__ __forceinline__ uint32_t pack2(float a, float b){
  return (uint32_t)f2bf(a) | ((uint32_t)f2bf(b) << 16);
}

__global__ void k_deg(const int* __restrict__ row, int E, int* __restrict__ deg){
  int i = blockIdx.x * blockDim.x + threadIdx.x;
  if (i < E) atomicAdd(&deg[row[i]], 1);
}

__global__ void k_r(const int* __restrict__ deg, float* __restrict__ r, int n){
  int i = blockIdx.x * blockDim.x + threadIdx.x;
  if (i < n) r[i] = 1.0f / (float)(deg[i] + 1);
}

__global__ void k_rowptr(const int* __restrict__ row, int E, int n, int* __restrict__ rp){
  int i = blockIdx.x * blockDim.x + threadIdx.x;
  if (i <= n){
    int lo = 0, hi = E;
    while (lo < hi){
      int mid = (lo + hi) >> 1;
      if (row[mid] < i) lo = mid + 1; else hi = mid;
    }
    rp[i] = lo;
  }
}

// bf16-transpose weights: W1T/W2T [l][n][k], Wl1T [n][k] (k<256), Wl2T [n][k]
__global__ void k_wprep(const float* __restrict__ W1, const float* __restrict__ W2,
                        const float* __restrict__ Wl1, const float* __restrict__ Wl2,
                        uint16_t* __restrict__ W1T, uint16_t* __restrict__ W2T,
                        uint16_t* __restrict__ Wl1T, uint16_t* __restrict__ Wl2T){
  int idx = blockIdx.x * blockDim.x + threadIdx.x;
  if (idx < 4 * 128 * 128){
    int l = idx >> 14, rem = idx & 16383, n = rem >> 7, k = rem & 127;
    W1T[idx] = f2bf(W1[l * 16384 + k * 128 + n]);
    W2T[idx] = f2bf(W2[l * 16384 + k * 128 + n]);
  }
  if (idx < 128 * 256){
    int n = idx >> 8, k = idx & 255;
    Wl1T[idx] = f2bf(Wl1[k * 128 + n]);
  }
  if (idx < 64 * 128){
    int n = idx >> 7, k = idx & 127;
    Wl2T[idx] = f2bf(Wl2[k * 64 + n]);
  }
}

// h = relu(x @ W_lin1 + b) via MFMA. 64-node tile, wave w owns cols [32w,32w+32).
__launch_bounds__(256)
__global__ void k_lin1m(const float* __restrict__ x, const uint16_t* __restrict__ Wl1T,
                        const float* __restrict__ b, uint16_t* __restrict__ h){
  __shared__ __align__(16) uint16_t Xs[64][264];   // 256 + 8 pad, row stride 528B
  const int tid = threadIdx.x;
  const int node0 = blockIdx.x * 64;
  const int wv = tid >> 6, lane = tid & 63, lr = lane & 15, lg = lane >> 4;

  // stage x -> bf16 LDS, fully coalesced float4 loads
  #pragma unroll
  for (int i = 0; i < 16; ++i){
    int fi = tid + i * 256;
    int rrow = fi >> 6, c4 = (fi & 63) * 4;
    int nd = node0 + rrow;
    float4 f = (nd < NN) ? *(const float4*)(x + (size_t)nd * ICH + c4)
                         : make_float4(0.f, 0.f, 0.f, 0.f);
    *(uint2*)&Xs[rrow][c4] = make_uint2(pack2(f.x, f.y), pack2(f.z, f.w));
  }
  __syncthreads();

  // B fragments: wave's 2 col-tiles, K=256 -> 8 ksteps
  bf16x8 bfr[2][8];
  #pragma unroll
  for (int n2 = 0; n2 < 2; ++n2){
    const int n = (2 * wv + n2) * 16 + lr;
    const uint16_t* bp = Wl1T + (size_t)n * 256 + lg * 8;
    #pragma unroll
    for (int ks = 0; ks < 8; ++ks)
      bfr[n2][ks] = __builtin_bit_cast(bf16x8, *(const uint4*)(bp + ks * 32));
  }
  float bias[2] = {b[(2 * wv + 0) * 16 + lr], b[(2 * wv + 1) * 16 + lr]};

  #pragma unroll
  for (int rt = 0; rt < 4; ++rt){
    const int row = rt * 16 + lr;
    bf16x8 af[8];
    #pragma unroll
    for (int ks = 0; ks < 8; ++ks)
      af[ks] = __builtin_bit_cast(bf16x8, *(const uint4*)&Xs[row][ks * 32 + lg * 8]);
    #pragma unroll
    for (int n2 = 0; n2 < 2; ++n2){
      f32x4 d = (f32x4){0.f, 0.f, 0.f, 0.f};
      #pragma unroll
      for (int ks = 0; ks < 8; ++ks)
        d = __builtin_amdgcn_mfma_f32_16x16x32_bf16(af[ks], bfr[n2][ks], d, 0, 0, 0);
      const int ncol = (2 * wv + n2) * 16 + lr;
      #pragma unroll
      for (int q = 0; q < 4; ++q){
        int nd = node0 + rt * 16 + lg * 4 + q;
        if (nd < NN){
          float v = d[q] + bias[n2];
          h[(size_t)nd * HID + ncol] = f2bf(v > 0.f ? v : 0.f);
        }
      }
    }
  }
}

// one wave per node: P = S h, T1 = S(r.h), T2 = S(r^2.h)
// explicit 16-wide gather panels: 16 independent loads in flight before use.
__launch_bounds__(256)
__global__ void k_spmmA(const int* __restrict__ col, const int* __restrict__ rp,
                        const float* __restrict__ r, const uint32_t* __restrict__ h,
                        uint32_t* __restrict__ P, uint32_t* __restrict__ T1,
                        uint32_t* __restrict__ T2){
  int wid  = (blockIdx.x * blockDim.x + threadIdx.x) >> 6;
  int lane = threadIdx.x & 63;
  if (wid >= NN) return;
  int e0 = rp[wid], e1 = rp[wid + 1];
  float a0 = 0, b0 = 0, a1 = 0, b1 = 0, a2 = 0, b2 = 0;
  for (int base = e0; base < e1; base += 64){
    int tot = e1 - base;
    int cnt = tot < 64 ? tot : 64;
    int jv  = (lane < cnt) ? col[base + lane] : 0;
    int rvb = (lane < cnt) ? __builtin_bit_cast(int, r[jv]) : 0;
    int k = 0;
    for (; k + 16 <= cnt; k += 16){
      uint32_t hv[16];
      #pragma unroll
      for (int t = 0; t < 16; ++t){
        int j = __builtin_amdgcn_readlane(jv, k + t);
        hv[t] = h[((uint32_t)j << 6) + lane];
      }
      #pragma unroll
      for (int t = 0; t < 16; ++t){
        float rj = __builtin_bit_cast(float, __builtin_amdgcn_readlane(rvb, k + t));
        float r2 = rj * rj;
        float x0 = __builtin_bit_cast(float, hv[t] << 16);
        float x1 = __builtin_bit_cast(float, hv[t] & 0xFFFF0000u);
        a0 += x0;               b0 += x1;
        a1 = fmaf(rj, x0, a1);  b1 = fmaf(rj, x1, b1);
        a2 = fmaf(r2, x0, a2);  b2 = fmaf(r2, x1, b2);
      }
    }
    for (; k + 4 <= cnt; k += 4){
      uint32_t hv[4];
      #pragma unroll
      for (int t = 0; t < 4; ++t){
        int j = __builtin_amdgcn_readlane(jv, k + t);
        hv[t] = h[((uint32_t)j << 6) + lane];
      }
      #pragma unroll
      for (int t = 0; t < 4; ++t){
        float rj = __builtin_bit_cast(float, __builtin_amdgcn_readlane(rvb, k + t));
        float r2 = rj * rj;
        float x0 = __builtin_bit_cast(float, hv[t] << 16);
        float x1 = __builtin_bit_cast(float, hv[t] & 0xFFFF0000u);
        a0 += x0;               b0 += x1;
        a1 = fmaf(rj, x0, a1);  b1 = fmaf(rj, x1, b1);
        a2 = fmaf(r2, x0, a2);  b2 = fmaf(r2, x1, b2);
      }
    }
    for (; k < cnt; ++k){
      int j = __builtin_amdgcn_readlane(jv, k);
      float rj = __builtin_bit_cast(float, __builtin_amdgcn_readlane(rvb, k));
      float r2 = rj * rj;
      uint32_t hv = h[((uint32_t)j << 6) + lane];
      float x0 = __builtin_bit_cast(float, hv << 16);
      float x1 = __builtin_bit_cast(float, hv & 0xFFFF0000u);
      a0 += x0;               b0 += x1;
      a1 = fmaf(rj, x0, a1);  b1 = fmaf(rj, x1, b1);
      a2 = fmaf(r2, x0, a2);  b2 = fmaf(r2, x1, b2);
    }
  }
  size_t o = (size_t)wid * 64 + lane;
  P[o]  = pack2(a0, b0);
  T1[o] = pack2(a1, b1);
  T2[o] = pack2(a2, b2);
}

// Q1 = S(r.P), Q2 = S(r^2.P) — same panel structure
__launch_bounds__(256)
__global__ void k_spmmB(const int* __restrict__ col, const int* __restrict__ rp,
                        const float* __restrict__ r, const uint32_t* __restrict__ Pm,
                        uint32_t* __restrict__ Q1, uint32_t* __restrict__ Q2){
  int wid  = (blockIdx.x * blockDim.x + threadIdx.x) >> 6;
  int lane = threadIdx.x & 63;
  if (wid >= NN) return;
  int e0 = rp[wid], e1 = rp[wid + 1];
  float a1 = 0, b1 = 0, a2 = 0, b2 = 0;
  for (int base = e0; base < e1; base += 64){
    int tot = e1 - base;
    int cnt = tot < 64 ? tot : 64;
    int jv  = (lane < cnt) ? col[base + lane] : 0;
    int rvb = (lane < cnt) ? __builtin_bit_cast(int, r[jv]) : 0;
    int k = 0;
    for (; k + 16 <= cnt; k += 16){
      uint32_t pv[16];
      #pragma unroll
      for (int t = 0; t < 16; ++t){
        int j = __builtin_amdgcn_readlane(jv, k + t);
        pv[t] = Pm[((uint32_t)j << 6) + lane];
      }
      #pragma unroll
      for (int t = 0; t < 16; ++t){
        float rj = __builtin_bit_cast(float, __builtin_amdgcn_readlane(rvb, k + t));
        float r2 = rj * rj;
        float x0 = __builtin_bit_cast(float, pv[t] << 16);
        float x1 = __builtin_bit_cast(float, pv[t] & 0xFFFF0000u);
        a1 = fmaf(rj, x0, a1);  b1 = fmaf(rj, x1, b1);
        a2 = fmaf(r2, x0, a2);  b2 = fmaf(r2, x1, b2);
      }
    }
    for (; k + 4 <= cnt; k += 4){
      uint32_t pv[4];
      #pragma unroll
      for (int t = 0; t < 4; ++t){
        int j = __builtin_amdgcn_readlane(jv, k + t);
        pv[t] = Pm[((uint32_t)j << 6) + lane];
      }
      #pragma unroll
      for (int t = 0; t < 4; ++t){
        float rj = __builtin_bit_cast(float, __builtin_amdgcn_readlane(rvb, k + t));
        float r2 = rj * rj;
        float x0 = __builtin_bit_cast(float, pv[t] << 16);
        float x1 = __builtin_bit_cast(float, pv[t] & 0xFFFF0000u);
        a1 = fmaf(rj, x0, a1);  b1 = fmaf(rj, x1, b1);
        a2 = fmaf(r2, x0, a2);  b2 = fmaf(r2, x1, b2);
      }
    }
    for (; k < cnt; ++k){
      int j = __builtin_amdgcn_readlane(jv, k);
      float rj = __builtin_bit_cast(float, __builtin_amdgcn_readlane(rvb, k));
      float r2 = rj * rj;
      uint32_t pv = Pm[((uint32_t)j << 6) + lane];
      float x0 = __builtin_bit_cast(float, pv << 16);
      float x1 = __builtin_bit_cast(float, pv & 0xFFFF0000u);
      a1 = fmaf(rj, x0, a1);  b1 = fmaf(rj, x1, b1);
      a2 = fmaf(r2, x0, a2);  b2 = fmaf(r2, x1, b2);
    }
  }
  size_t o = (size_t)wid * 64 + lane;
  Q1[o] = pack2(a1, b1);
  Q2[o] = pack2(a2, b2);
}

__device__ __forceinline__ void ld4u(const uint32_t* p, uint32_t a[4]){
  uint4 t = *(const uint4*)p;
  a[0] = t.x; a[1] = t.y; a[2] = t.z; a[3] = t.w;
}

// MFMA epilogue (unchanged)
__launch_bounds__(256)
__global__ void k_epi2(const uint32_t* __restrict__ h,  const uint32_t* __restrict__ P,
                       const uint32_t* __restrict__ T1, const uint32_t* __restrict__ T2,
                       const uint32_t* __restrict__ Q1, const uint32_t* __restrict__ Q2,
                       const float* __restrict__ r,
                       const uint16_t* __restrict__ W1T, const uint16_t* __restrict__ W2T,
                       const uint16_t* __restrict__ Wl2T, const float* __restrict__ b2,
                       float* __restrict__ out){
  __shared__ __align__(16) uint32_t Mu[2][64][68];   // bf16 [64][136], row stride 272B
  const int tid = threadIdx.x;
  const int node0 = blockIdx.x * 64;

  const int nb = tid >> 2;
  const int qc = tid & 3;
  const int nd = node0 + nb;
  const bool valid = nd < NN;
  const float rv = valid ? r[nd] : 1.f;
  const size_t ub = (size_t)nd * 64;

  const int wv   = tid >> 6;
  const int lane = tid & 63;
  const int lr   = lane & 15;
  const int lg   = lane >> 4;

  f32x4 acc[4][2];
  #pragma unroll
  for (int rt = 0; rt < 4; ++rt)
    #pragma unroll
    for (int n2 = 0; n2 < 2; ++n2)
      acc[rt][n2] = (f32x4){0.f, 0.f, 0.f, 0.f};

  #pragma unroll
  for (int l = 0; l < 4; ++l){
    __syncthreads();
    #pragma unroll
    for (int c = 0; c < 4; ++c){
      const int ui = qc * 4 + c * 16;
      uint32_t ah[4], ap[4], at1[4], at2[4], aq1[4], aq2[4];
      uint32_t o1[4], o2[4];
      if (valid){
        ld4u(h + ub + ui, ah);
        ld4u(P + ub + ui, ap);
        if (l == 1){ ld4u(Q1 + ub + ui, aq1); ld4u(T1 + ub + ui, at1); }
        if (l == 2){ ld4u(Q2 + ub + ui, aq2); ld4u(T1 + ub + ui, at1); ld4u(T2 + ub + ui, at2); }
        #pragma unroll
        for (int wq = 0; wq < 4; ++wq){
          float m1s[2], m2s[2];
          #pragma unroll
          for (int s = 0; s < 2; ++s){
            float hh = bf2f((uint16_t)(s ? (ah[wq] >> 16) : ah[wq]));
            float pp = bf2f((uint16_t)(s ? (ap[wq] >> 16) : ap[wq]));
            if (l == 0){
              float F = rv * (pp + hh);
              m1s[s] = F; m2s[s] = hh - F;
            } else if (l == 1){
              float t1 = bf2f((uint16_t)(s ? (at1[wq] >> 16) : at1[wq]));
              float q1 = bf2f((uint16_t)(s ? (aq1[wq] >> 16) : aq1[wq]));
              float F = rv * (pp + hh);
              float G = hh - F;
              m1s[s] = rv * (pp - q1 - t1 + G);
              m2s[s] = F - rv * (q1 + t1 + F);
            } else if (l == 2){
              float t1 = bf2f((uint16_t)(s ? (at1[wq] >> 16) : at1[wq]));
              float t2 = bf2f((uint16_t)(s ? (at2[wq] >> 16) : at2[wq]));
              float q2 = bf2f((uint16_t)(s ? (aq2[wq] >> 16) : aq2[wq]));
              float omr = 1.f - rv;
              float G2 = rv * rv * pp + omr * omr * hh;
              m1s[s] = rv * (q2 + pp - 2.f * t1 + t2 + G2);
              float F2 = rv * rv * (pp + hh);
              m2s[s] = F2 - rv * (q2 + t2 + F2);
            } else {
              float omr = 1.f - rv;
              float r3 = rv * rv * rv;
              m1s[s] = omr * omr * omr * hh - r3 * pp;
              m2s[s] = r3 * (pp + hh);
            }
          }
          o1[wq] = pack2(m1s[0], m1s[1]);
          o2[wq] = pack2(m2s[0], m2s[1]);
        }
      } else {
        #pragma unroll
        for (int wq = 0; wq < 4; ++wq){ o1[wq] = 0u; o2[wq] = 0u; }
      }
      *(uint4*)&Mu[0][nb][ui] = make_uint4(o1[0], o1[1], o1[2], o1[3]);
      *(uint4*)&Mu[1][nb][ui] = make_uint4(o2[0], o2[1], o2[2], o2[3]);
    }
    __syncthreads();

    #pragma unroll
    for (int m = 0; m < 2; ++m){
      const uint16_t* Wt = (m ? W2T : W1T) + (size_t)l * 128 * 128;
      bf16x8 bfr[2][4];
      #pragma unroll
      for (int n2 = 0; n2 < 2; ++n2){
        const int n = (2 * wv + n2) * 16 + lr;
        const uint16_t* bp = Wt + (size_t)n * 128 + lg * 8;
        #pragma unroll
        for (int ks = 0; ks < 4; ++ks)
          bfr[n2][ks] = __builtin_bit_cast(bf16x8, *(const uint4*)(bp + ks * 32));
      }
      #pragma unroll
      for (int rt = 0; rt < 4; ++rt){
        const int row = rt * 16 + lr;
        bf16x8 af[4];
        #pragma unroll
        for (int ks = 0; ks < 4; ++ks)
          af[ks] = __builtin_bit_cast(bf16x8, *(const uint4*)&Mu[m][row][ks * 16 + lg * 4]);
        #pragma unroll
        for (int n2 = 0; n2 < 2; ++n2){
          f32x4 d = (f32x4){0.f, 0.f, 0.f, 0.f};
          #pragma unroll
          for (int ks = 0; ks < 4; ++ks)
            d = __builtin_amdgcn_mfma_f32_16x16x32_bf16(af[ks], bfr[n2][ks], d, 0, 0, 0);
          #pragma unroll
          for (int q = 0; q < 4; ++q)
            acc[rt][n2][q] += (d[q] > 0.f ? d[q] : 0.f);
        }
      }
    }
  }

  __syncthreads();
  uint16_t* Mb = (uint16_t*)&Mu[0][0][0];
  #pragma unroll
  for (int rt = 0; rt < 4; ++rt)
    #pragma unroll
    for (int n2 = 0; n2 < 2; ++n2)
      #pragma unroll
      for (int q = 0; q < 4; ++q){
        int row = rt * 16 + lg * 4 + q;
        int colb = (2 * wv + n2) * 16 + lr;
        Mb[row * 136 + colb] = f2bf(acc[rt][n2][q] * 0.125f);
      }
  __syncthreads();

  const int arow = 16 * wv + lr;
  bf16x8 af2[4];
  #pragma unroll
  for (int ks = 0; ks < 4; ++ks)
    af2[ks] = __builtin_bit_cast(bf16x8, *(const uint4*)&Mu[0][arow][ks * 16 + lg * 4]);
  #pragma unroll
  for (int nt = 0; nt < 4; ++nt){
    f32x4 d = (f32x4){0.f, 0.f, 0.f, 0.f};
    #pragma unroll
    for (int ks = 0; ks < 4; ++ks){
      bf16x8 bfr = __builtin_bit_cast(bf16x8,
          *(const uint4*)(Wl2T + (size_t)(nt * 16 + lr) * 128 + ks * 32 + lg * 8));
      d = __builtin_amdgcn_mfma_f32_16x16x32_bf16(af2[ks], bfr, d, 0, 0, 0);
    }
    float bias = b2[nt * 16 + lr];
    #pragma unroll
    for (int q = 0; q < 4; ++q){
      int rr = node0 + 16 * wv + lg * 4 + q;
      if (rr < NN) out[(size_t)rr * OUTF + nt * 16 + lr] = d[q] + bias;
    }
  }
}

extern "C" void kernel_launch(void* const* d_in, const int* in_sizes, int n_in,
                              void* d_out, int out_size, void* d_ws, size_t ws_size,
                              hipStream_t stream){
  const float* x   = (const float*)d_in[0];
  const float* Wl1 = (const float*)d_in[1];
  const float* bl1 = (const float*)d_in[2];
  const float* W1  = (const float*)d_in[3];
  const float* W2  = (const float*)d_in[4];
  const float* Wl2 = (const float*)d_in[5];
  const float* bl2 = (const float*)d_in[6];
  const int*   ei  = (const int*)d_in[7];
  int E = in_sizes[7] / 2;
  const int* rowp = ei;
  const int* colp = ei + E;

  char* ws = (char*)d_ws;
  size_t off = 0;
  auto alloc = [&](size_t bytes) -> void* {
    void* p = ws + off;
    off += (bytes + 255) & ~(size_t)255;
    return p;
  };
  const size_t MATB = (size_t)NN * HID * 2;
  uint32_t* h  = (uint32_t*)alloc(MATB);
  uint32_t* P  = (uint32_t*)alloc(MATB);
  uint32_t* T1 = (uint32_t*)alloc(MATB);
  uint32_t* T2 = (uint32_t*)alloc(MATB);
  uint32_t* Q1 = (uint32_t*)alloc(MATB);
  uint32_t* Q2 = (uint32_t*)alloc(MATB);
  float* r  = (float*)alloc((size_t)NN * 4);
  int* deg  = (int*)alloc((size_t)NN * 4);
  int* rp   = (int*)alloc((size_t)(NN + 1) * 4);
  uint16_t* W1T  = (uint16_t*)alloc((size_t)4 * 128 * 128 * 2);
  uint16_t* W2T  = (uint16_t*)alloc((size_t)4 * 128 * 128 * 2);
  uint16_t* Wl1T = (uint16_t*)alloc((size_t)128 * 256 * 2);
  uint16_t* Wl2T = (uint16_t*)alloc((size_t)64 * 128 * 2);

  hipMemsetAsync(deg, 0, (size_t)NN * 4, stream);
  k_wprep<<<(4 * 128 * 128 + 255) / 256, 256, 0, stream>>>(W1, W2, Wl1, Wl2,
                                                           W1T, W2T, Wl1T, Wl2T);
  k_deg<<<(E + 255) / 256, 256, 0, stream>>>(rowp, E, deg);
  k_r<<<(NN + 255) / 256, 256, 0, stream>>>(deg, r, NN);
  k_rowptr<<<(NN + 1 + 255) / 256, 256, 0, stream>>>(rowp, E, NN, rp);
  k_lin1m<<<(NN + 63) / 64, 256, 0, stream>>>(x, Wl1T, bl1, (uint16_t*)h);
  k_spmmA<<<(NN + 3) / 4, 256, 0, stream>>>(colp, rp, r, h, P, T1, T2);
  k_spmmB<<<(NN + 3) / 4, 256, 0, stream>>>(colp, rp, r, P, Q1, Q2);
  k_epi2<<<(NN + 63) / 64, 256, 0, stream>>>(h, P, T1, T2, Q1, Q2, r,
                                             W1T, W2T, Wl2T, bl2, (float*)d_out);
}

// Round 5
// 447.277 us; speedup vs baseline: 4.6403x; 1.3527x over previous
//
#include <hip/hip_runtime.h>
#include <hip/hip_bf16.h>
#include <stdint.h>

#define NN   100000
#define ICH  256
#define HID  128
#define OUTF 64

typedef float  f32x4  __attribute__((ext_vector_type(4)));
typedef __bf16 bf16x8 __attribute__((ext_vector_type(8)));

__device__ __forceinline__ float bf2f(uint16_t u){
  union { uint32_t i; float f; } v; v.i = ((uint32_t)u) << 16; return v.f;
}
__device__ __forceinline__ uint16_t f2bf(float f){
  union { float f; uint32_t i; } v; v.f = f;
  uint32_t i = v.i;
  return (uint16_t)((i + 0x7FFFu + ((i >> 16) & 1u)) >> 16);
}
__device__ __forceinline__ uint32_t pack2(float a, float b){
  return (uint32_t)f2bf(a) | ((uint32_t)f2bf(b) << 16);
}

// Fused CSR build: edges sorted by src. Thread i binary-searches row starts for
// i and i+1 -> rp[i] and r[i] = 1/(deg_i+1). (replaces k_deg's 3.2M atomics)
__global__ void k_csr(const int* __restrict__ row, int E, int n,
                      int* __restrict__ rp, float* __restrict__ r){
  int i = blockIdx.x * blockDim.x + threadIdx.x;
  if (i > n) return;
  int lo = 0, hi = E;
  while (lo < hi){
    int mid = (lo + hi) >> 1;
    if (row[mid] < i) lo = mid + 1; else hi = mid;
  }
  rp[i] = lo;
  if (i < n){
    int lo2 = lo, hi2 = E;
    while (lo2 < hi2){
      int mid = (lo2 + hi2) >> 1;
      if (row[mid] < i + 1) lo2 = mid + 1; else hi2 = mid;
    }
    r[i] = 1.0f / (float)(lo2 - lo + 1);
  }
}

// bf16-transpose weights: W1T/W2T [l][n][k], Wl1T [n][k] (k<256), Wl2T [n][k]
__global__ void k_wprep(const float* __restrict__ W1, const float* __restrict__ W2,
                        const float* __restrict__ Wl1, const float* __restrict__ Wl2,
                        uint16_t* __restrict__ W1T, uint16_t* __restrict__ W2T,
                        uint16_t* __restrict__ Wl1T, uint16_t* __restrict__ Wl2T){
  int idx = blockIdx.x * blockDim.x + threadIdx.x;
  if (idx < 4 * 128 * 128){
    int l = idx >> 14, rem = idx & 16383, n = rem >> 7, k = rem & 127;
    W1T[idx] = f2bf(W1[l * 16384 + k * 128 + n]);
    W2T[idx] = f2bf(W2[l * 16384 + k * 128 + n]);
  }
  if (idx < 128 * 256){
    int n = idx >> 8, k = idx & 255;
    Wl1T[idx] = f2bf(Wl1[k * 128 + n]);
  }
  if (idx < 64 * 128){
    int n = idx >> 7, k = idx & 127;
    Wl2T[idx] = f2bf(Wl2[k * 64 + n]);
  }
}

// h = relu(x @ W_lin1 + b) via MFMA. 64-node tile, wave w owns cols [32w,32w+32).
__launch_bounds__(256)
__global__ void k_lin1m(const float* __restrict__ x, const uint16_t* __restrict__ Wl1T,
                        const float* __restrict__ b, uint16_t* __restrict__ h){
  __shared__ __align__(16) uint16_t Xs[64][264];   // 256 + 8 pad, row stride 528B
  const int tid = threadIdx.x;
  const int node0 = blockIdx.x * 64;
  const int wv = tid >> 6, lane = tid & 63, lr = lane & 15, lg = lane >> 4;

  // stage x -> bf16 LDS, fully coalesced float4 loads
  #pragma unroll
  for (int i = 0; i < 16; ++i){
    int fi = tid + i * 256;
    int rrow = fi >> 6, c4 = (fi & 63) * 4;
    int nd = node0 + rrow;
    float4 f = (nd < NN) ? *(const float4*)(x + (size_t)nd * ICH + c4)
                         : make_float4(0.f, 0.f, 0.f, 0.f);
    *(uint2*)&Xs[rrow][c4] = make_uint2(pack2(f.x, f.y), pack2(f.z, f.w));
  }
  __syncthreads();

  // B fragments: wave's 2 col-tiles, K=256 -> 8 ksteps
  bf16x8 bfr[2][8];
  #pragma unroll
  for (int n2 = 0; n2 < 2; ++n2){
    const int n = (2 * wv + n2) * 16 + lr;
    const uint16_t* bp = Wl1T + (size_t)n * 256 + lg * 8;
    #pragma unroll
    for (int ks = 0; ks < 8; ++ks)
      bfr[n2][ks] = __builtin_bit_cast(bf16x8, *(const uint4*)(bp + ks * 32));
  }
  float bias[2] = {b[(2 * wv + 0) * 16 + lr], b[(2 * wv + 1) * 16 + lr]};

  #pragma unroll
  for (int rt = 0; rt < 4; ++rt){
    const int row = rt * 16 + lr;
    bf16x8 af[8];
    #pragma unroll
    for (int ks = 0; ks < 8; ++ks)
      af[ks] = __builtin_bit_cast(bf16x8, *(const uint4*)&Xs[row][ks * 32 + lg * 8]);
    #pragma unroll
    for (int n2 = 0; n2 < 2; ++n2){
      f32x4 d = (f32x4){0.f, 0.f, 0.f, 0.f};
      #pragma unroll
      for (int ks = 0; ks < 8; ++ks)
        d = __builtin_amdgcn_mfma_f32_16x16x32_bf16(af[ks], bfr[n2][ks], d, 0, 0, 0);
      const int ncol = (2 * wv + n2) * 16 + lr;
      #pragma unroll
      for (int q = 0; q < 4; ++q){
        int nd = node0 + rt * 16 + lg * 4 + q;
        if (nd < NN){
          float v = d[q] + bias[n2];
          h[(size_t)nd * HID + ncol] = f2bf(v > 0.f ? v : 0.f);
        }
      }
    }
  }
}

// one wave per node: P = S h, T1 = S(r.h), T2 = S(r^2.h)
// explicit 16-wide gather panels: 16 independent loads in flight before use.
__launch_bounds__(256)
__global__ void k_spmmA(const int* __restrict__ col, const int* __restrict__ rp,
                        const float* __restrict__ r, const uint32_t* __restrict__ h,
                        uint32_t* __restrict__ P, uint32_t* __restrict__ T1,
                        uint32_t* __restrict__ T2){
  int wid  = (blockIdx.x * blockDim.x + threadIdx.x) >> 6;
  int lane = threadIdx.x & 63;
  if (wid >= NN) return;
  int e0 = rp[wid], e1 = rp[wid + 1];
  float a0 = 0, b0 = 0, a1 = 0, b1 = 0, a2 = 0, b2 = 0;
  for (int base = e0; base < e1; base += 64){
    int tot = e1 - base;
    int cnt = tot < 64 ? tot : 64;
    int jv  = (lane < cnt) ? col[base + lane] : 0;
    int rvb = (lane < cnt) ? __builtin_bit_cast(int, r[jv]) : 0;
    int k = 0;
    for (; k + 16 <= cnt; k += 16){
      uint32_t hv[16];
      #pragma unroll
      for (int t = 0; t < 16; ++t){
        int j = __builtin_amdgcn_readlane(jv, k + t);
        hv[t] = h[((uint32_t)j << 6) + lane];
      }
      #pragma unroll
      for (int t = 0; t < 16; ++t){
        float rj = __builtin_bit_cast(float, __builtin_amdgcn_readlane(rvb, k + t));
        float r2 = rj * rj;
        float x0 = __builtin_bit_cast(float, hv[t] << 16);
        float x1 = __builtin_bit_cast(float, hv[t] & 0xFFFF0000u);
        a0 += x0;               b0 += x1;
        a1 = fmaf(rj, x0, a1);  b1 = fmaf(rj, x1, b1);
        a2 = fmaf(r2, x0, a2);  b2 = fmaf(r2, x1, b2);
      }
    }
    for (; k + 4 <= cnt; k += 4){
      uint32_t hv[4];
      #pragma unroll
      for (int t = 0; t < 4; ++t){
        int j = __builtin_amdgcn_readlane(jv, k + t);
        hv[t] = h[((uint32_t)j << 6) + lane];
      }
      #pragma unroll
      for (int t = 0; t < 4; ++t){
        float rj = __builtin_bit_cast(float, __builtin_amdgcn_readlane(rvb, k + t));
        float r2 = rj * rj;
        float x0 = __builtin_bit_cast(float, hv[t] << 16);
        float x1 = __builtin_bit_cast(float, hv[t] & 0xFFFF0000u);
        a0 += x0;               b0 += x1;
        a1 = fmaf(rj, x0, a1);  b1 = fmaf(rj, x1, b1);
        a2 = fmaf(r2, x0, a2);  b2 = fmaf(r2, x1, b2);
      }
    }
    for (; k < cnt; ++k){
      int j = __builtin_amdgcn_readlane(jv, k);
      float rj = __builtin_bit_cast(float, __builtin_amdgcn_readlane(rvb, k));
      float r2 = rj * rj;
      uint32_t hv = h[((uint32_t)j << 6) + lane];
      float x0 = __builtin_bit_cast(float, hv << 16);
      float x1 = __builtin_bit_cast(float, hv & 0xFFFF0000u);
      a0 += x0;               b0 += x1;
      a1 = fmaf(rj, x0, a1);  b1 = fmaf(rj, x1, b1);
      a2 = fmaf(r2, x0, a2);  b2 = fmaf(r2, x1, b2);
    }
  }
  size_t o = (size_t)wid * 64 + lane;
  P[o]  = pack2(a0, b0);
  T1[o] = pack2(a1, b1);
  T2[o] = pack2(a2, b2);
}

// Q1 = S(r.P), Q2 = S(r^2.P) — same panel structure
__launch_bounds__(256)
__global__ void k_spmmB(const int* __restrict__ col, const int* __restrict__ rp,
                        const float* __restrict__ r, const uint32_t* __restrict__ Pm,
                        uint32_t* __restrict__ Q1, uint32_t* __restrict__ Q2){
  int wid  = (blockIdx.x * blockDim.x + threadIdx.x) >> 6;
  int lane = threadIdx.x & 63;
  if (wid >= NN) return;
  int e0 = rp[wid], e1 = rp[wid + 1];
  float a1 = 0, b1 = 0, a2 = 0, b2 = 0;
  for (int base = e0; base < e1; base += 64){
    int tot = e1 - base;
    int cnt = tot < 64 ? tot : 64;
    int jv  = (lane < cnt) ? col[base + lane] : 0;
    int rvb = (lane < cnt) ? __builtin_bit_cast(int, r[jv]) : 0;
    int k = 0;
    for (; k + 16 <= cnt; k += 16){
      uint32_t pv[16];
      #pragma unroll
      for (int t = 0; t < 16; ++t){
        int j = __builtin_amdgcn_readlane(jv, k + t);
        pv[t] = Pm[((uint32_t)j << 6) + lane];
      }
      #pragma unroll
      for (int t = 0; t < 16; ++t){
        float rj = __builtin_bit_cast(float, __builtin_amdgcn_readlane(rvb, k + t));
        float r2 = rj * rj;
        float x0 = __builtin_bit_cast(float, pv[t] << 16);
        float x1 = __builtin_bit_cast(float, pv[t] & 0xFFFF0000u);
        a1 = fmaf(rj, x0, a1);  b1 = fmaf(rj, x1, b1);
        a2 = fmaf(r2, x0, a2);  b2 = fmaf(r2, x1, b2);
      }
    }
    for (; k + 4 <= cnt; k += 4){
      uint32_t pv[4];
      #pragma unroll
      for (int t = 0; t < 4; ++t){
        int j = __builtin_amdgcn_readlane(jv, k + t);
        pv[t] = Pm[((uint32_t)j << 6) + lane];
      }
      #pragma unroll
      for (int t = 0; t < 4; ++t){
        float rj = __builtin_bit_cast(float, __builtin_amdgcn_readlane(rvb, k + t));
        float r2 = rj * rj;
        float x0 = __builtin_bit_cast(float, pv[t] << 16);
        float x1 = __builtin_bit_cast(float, pv[t] & 0xFFFF0000u);
        a1 = fmaf(rj, x0, a1);  b1 = fmaf(rj, x1, b1);
        a2 = fmaf(r2, x0, a2);  b2 = fmaf(r2, x1, b2);
      }
    }
    for (; k < cnt; ++k){
      int j = __builtin_amdgcn_readlane(jv, k);
      float rj = __builtin_bit_cast(float, __builtin_amdgcn_readlane(rvb, k));
      float r2 = rj * rj;
      uint32_t pv = Pm[((uint32_t)j << 6) + lane];
      float x0 = __builtin_bit_cast(float, pv << 16);
      float x1 = __builtin_bit_cast(float, pv & 0xFFFF0000u);
      a1 = fmaf(rj, x0, a1);  b1 = fmaf(rj, x1, b1);
      a2 = fmaf(r2, x0, a2);  b2 = fmaf(r2, x1, b2);
    }
  }
  size_t o = (size_t)wid * 64 + lane;
  Q1[o] = pack2(a1, b1);
  Q2[o] = pack2(a2, b2);
}

__device__ __forceinline__ void ld4u(const uint32_t* p, uint32_t a[4]){
  uint4 t = *(const uint4*)p;
  a[0] = t.x; a[1] = t.y; a[2] = t.z; a[3] = t.w;
}

// MFMA epilogue (unchanged)
__launch_bounds__(256)
__global__ void k_epi2(const uint32_t* __restrict__ h,  const uint32_t* __restrict__ P,
                       const uint32_t* __restrict__ T1, const uint32_t* __restrict__ T2,
                       const uint32_t* __restrict__ Q1, const uint32_t* __restrict__ Q2,
                       const float* __restrict__ r,
                       const uint16_t* __restrict__ W1T, const uint16_t* __restrict__ W2T,
                       const uint16_t* __restrict__ Wl2T, const float* __restrict__ b2,
                       float* __restrict__ out){
  __shared__ __align__(16) uint32_t Mu[2][64][68];   // bf16 [64][136], row stride 272B
  const int tid = threadIdx.x;
  const int node0 = blockIdx.x * 64;

  const int nb = tid >> 2;
  const int qc = tid & 3;
  const int nd = node0 + nb;
  const bool valid = nd < NN;
  const float rv = valid ? r[nd] : 1.f;
  const size_t ub = (size_t)nd * 64;

  const int wv   = tid >> 6;
  const int lane = tid & 63;
  const int lr   = lane & 15;
  const int lg   = lane >> 4;

  f32x4 acc[4][2];
  #pragma unroll
  for (int rt = 0; rt < 4; ++rt)
    #pragma unroll
    for (int n2 = 0; n2 < 2; ++n2)
      acc[rt][n2] = (f32x4){0.f, 0.f, 0.f, 0.f};

  #pragma unroll
  for (int l = 0; l < 4; ++l){
    __syncthreads();
    #pragma unroll
    for (int c = 0; c < 4; ++c){
      const int ui = qc * 4 + c * 16;
      uint32_t ah[4], ap[4], at1[4], at2[4], aq1[4], aq2[4];
      uint32_t o1[4], o2[4];
      if (valid){
        ld4u(h + ub + ui, ah);
        ld4u(P + ub + ui, ap);
        if (l == 1){ ld4u(Q1 + ub + ui, aq1); ld4u(T1 + ub + ui, at1); }
        if (l == 2){ ld4u(Q2 + ub + ui, aq2); ld4u(T1 + ub + ui, at1); ld4u(T2 + ub + ui, at2); }
        #pragma unroll
        for (int wq = 0; wq < 4; ++wq){
          float m1s[2], m2s[2];
          #pragma unroll
          for (int s = 0; s < 2; ++s){
            float hh = bf2f((uint16_t)(s ? (ah[wq] >> 16) : ah[wq]));
            float pp = bf2f((uint16_t)(s ? (ap[wq] >> 16) : ap[wq]));
            if (l == 0){
              float F = rv * (pp + hh);
              m1s[s] = F; m2s[s] = hh - F;
            } else if (l == 1){
              float t1 = bf2f((uint16_t)(s ? (at1[wq] >> 16) : at1[wq]));
              float q1 = bf2f((uint16_t)(s ? (aq1[wq] >> 16) : aq1[wq]));
              float F = rv * (pp + hh);
              float G = hh - F;
              m1s[s] = rv * (pp - q1 - t1 + G);
              m2s[s] = F - rv * (q1 + t1 + F);
            } else if (l == 2){
              float t1 = bf2f((uint16_t)(s ? (at1[wq] >> 16) : at1[wq]));
              float t2 = bf2f((uint16_t)(s ? (at2[wq] >> 16) : at2[wq]));
              float q2 = bf2f((uint16_t)(s ? (aq2[wq] >> 16) : aq2[wq]));
              float omr = 1.f - rv;
              float G2 = rv * rv * pp + omr * omr * hh;
              m1s[s] = rv * (q2 + pp - 2.f * t1 + t2 + G2);
              float F2 = rv * rv * (pp + hh);
              m2s[s] = F2 - rv * (q2 + t2 + F2);
            } else {
              float omr = 1.f - rv;
              float r3 = rv * rv * rv;
              m1s[s] = omr * omr * omr * hh - r3 * pp;
              m2s[s] = r3 * (pp + hh);
            }
          }
          o1[wq] = pack2(m1s[0], m1s[1]);
          o2[wq] = pack2(m2s[0], m2s[1]);
        }
      } else {
        #pragma unroll
        for (int wq = 0; wq < 4; ++wq){ o1[wq] = 0u; o2[wq] = 0u; }
      }
      *(uint4*)&Mu[0][nb][ui] = make_uint4(o1[0], o1[1], o1[2], o1[3]);
      *(uint4*)&Mu[1][nb][ui] = make_uint4(o2[0], o2[1], o2[2], o2[3]);
    }
    __syncthreads();

    #pragma unroll
    for (int m = 0; m < 2; ++m){
      const uint16_t* Wt = (m ? W2T : W1T) + (size_t)l * 128 * 128;
      bf16x8 bfr[2][4];
      #pragma unroll
      for (int n2 = 0; n2 < 2; ++n2){
        const int n = (2 * wv + n2) * 16 + lr;
        const uint16_t* bp = Wt + (size_t)n * 128 + lg * 8;
        #pragma unroll
        for (int ks = 0; ks < 4; ++ks)
          bfr[n2][ks] = __builtin_bit_cast(bf16x8, *(const uint4*)(bp + ks * 32));
      }
      #pragma unroll
      for (int rt = 0; rt < 4; ++rt){
        const int row = rt * 16 + lr;
        bf16x8 af[4];
        #pragma unroll
        for (int ks = 0; ks < 4; ++ks)
          af[ks] = __builtin_bit_cast(bf16x8, *(const uint4*)&Mu[m][row][ks * 16 + lg * 4]);
        #pragma unroll
        for (int n2 = 0; n2 < 2; ++n2){
          f32x4 d = (f32x4){0.f, 0.f, 0.f, 0.f};
          #pragma unroll
          for (int ks = 0; ks < 4; ++ks)
            d = __builtin_amdgcn_mfma_f32_16x16x32_bf16(af[ks], bfr[n2][ks], d, 0, 0, 0);
          #pragma unroll
          for (int q = 0; q < 4; ++q)
            acc[rt][n2][q] += (d[q] > 0.f ? d[q] : 0.f);
        }
      }
    }
  }

  __syncthreads();
  uint16_t* Mb = (uint16_t*)&Mu[0][0][0];
  #pragma unroll
  for (int rt = 0; rt < 4; ++rt)
    #pragma unroll
    for (int n2 = 0; n2 < 2; ++n2)
      #pragma unroll
      for (int q = 0; q < 4; ++q){
        int row = rt * 16 + lg * 4 + q;
        int colb = (2 * wv + n2) * 16 + lr;
        Mb[row * 136 + colb] = f2bf(acc[rt][n2][q] * 0.125f);
      }
  __syncthreads();

  const int arow = 16 * wv + lr;
  bf16x8 af2[4];
  #pragma unroll
  for (int ks = 0; ks < 4; ++ks)
    af2[ks] = __builtin_bit_cast(bf16x8, *(const uint4*)&Mu[0][arow][ks * 16 + lg * 4]);
  #pragma unroll
  for (int nt = 0; nt < 4; ++nt){
    f32x4 d = (f32x4){0.f, 0.f, 0.f, 0.f};
    #pragma unroll
    for (int ks = 0; ks < 4; ++ks){
      bf16x8 bfr = __builtin_bit_cast(bf16x8,
          *(const uint4*)(Wl2T + (size_t)(nt * 16 + lr) * 128 + ks * 32 + lg * 8));
      d = __builtin_amdgcn_mfma_f32_16x16x32_bf16(af2[ks], bfr, d, 0, 0, 0);
    }
    float bias = b2[nt * 16 + lr];
    #pragma unroll
    for (int q = 0; q < 4; ++q){
      int rr = node0 + 16 * wv + lg * 4 + q;
      if (rr < NN) out[(size_t)rr * OUTF + nt * 16 + lr] = d[q] + bias;
    }
  }
}

extern "C" void kernel_launch(void* const* d_in, const int* in_sizes, int n_in,
                              void* d_out, int out_size, void* d_ws, size_t ws_size,
                              hipStream_t stream){
  const float* x   = (const float*)d_in[0];
  const float* Wl1 = (const float*)d_in[1];
  const float* bl1 = (const float*)d_in[2];
  const float* W1  = (const float*)d_in[3];
  const float* W2  = (const float*)d_in[4];
  const float* Wl2 = (const float*)d_in[5];
  const float* bl2 = (const float*)d_in[6];
  const int*   ei  = (const int*)d_in[7];
  int E = in_sizes[7] / 2;
  const int* rowp = ei;
  const int* colp = ei + E;

  char* ws = (char*)d_ws;
  size_t off = 0;
  auto alloc = [&](size_t bytes) -> void* {
    void* p = ws + off;
    off += (bytes + 255) & ~(size_t)255;
    return p;
  };
  const size_t MATB = (size_t)NN * HID * 2;
  uint32_t* h  = (uint32_t*)alloc(MATB);
  uint32_t* P  = (uint32_t*)alloc(MATB);
  uint32_t* T1 = (uint32_t*)alloc(MATB);
  uint32_t* T2 = (uint32_t*)alloc(MATB);
  uint32_t* Q1 = (uint32_t*)alloc(MATB);
  uint32_t* Q2 = (uint32_t*)alloc(MATB);
  float* r  = (float*)alloc((size_t)NN * 4);
  int* rp   = (int*)alloc((size_t)(NN + 1) * 4);
  uint16_t* W1T  = (uint16_t*)alloc((size_t)4 * 128 * 128 * 2);
  uint16_t* W2T  = (uint16_t*)alloc((size_t)4 * 128 * 128 * 2);
  uint16_t* Wl1T = (uint16_t*)alloc((size_t)128 * 256 * 2);
  uint16_t* Wl2T = (uint16_t*)alloc((size_t)64 * 128 * 2);

  k_wprep<<<(4 * 128 * 128 + 255) / 256, 256, 0, stream>>>(W1, W2, Wl1, Wl2,
                                                           W1T, W2T, Wl1T, Wl2T);
  k_csr<<<(NN + 1 + 255) / 256, 256, 0, stream>>>(rowp, E, NN, rp, r);
  k_lin1m<<<(NN + 63) / 64, 256, 0, stream>>>(x, Wl1T, bl1, (uint16_t*)h);
  k_spmmA<<<(NN + 3) / 4, 256, 0, stream>>>(colp, rp, r, h, P, T1, T2);
  k_spmmB<<<(NN + 3) / 4, 256, 0, stream>>>(colp, rp, r, P, Q1, Q2);
  k_epi2<<<(NN + 63) / 64, 256, 0, stream>>>(h, P, T1, T2, Q1, Q2, r,
                                             W1T, W2T, Wl2T, bl2, (float*)d_out);
}